// Round 5
// baseline (777.147 us; speedup 1.0000x reference)
//
#include <hip/hip_runtime.h>
#include <hip/hip_fp16.h>
#include <math.h>

constexpr int NN  = 50000;   // nodes
constexpr int EE  = 800000;  // edges
constexpr int INF_ = 256;    // input feat
constexpr int HF  = 128;     // hidden
constexpr int CC  = 50;      // classes
constexpr long NH = (long)NN * HF;
constexpr int NSL = 32;          // edge slices
constexpr int ESL = EE / NSL;    // 25000 edges per slice
constexpr int CHK = 12500;       // nodes per chunk (4 chunks), 50KB LDS
#define EPSV 1e-5f

enum { EPI_RELU = 0, EPI_NONE = 1, EPI_BN = 2, EPI_BN_RES = 3 };
enum { H16_NONE = 0, H16_RAW = 1, H16_SCALED = 2 };

typedef __attribute__((ext_vector_type(4))) float f32x4;
typedef __attribute__((ext_vector_type(8))) short bf16x8;

__device__ __forceinline__ ushort f2bf(float f) {
  union { float f; unsigned u; } v; v.f = f;
  unsigned r = (v.u + 0x7fffu + ((v.u >> 16) & 1u)) >> 16;  // RNE
  return (ushort)r;
}
__device__ __forceinline__ float bf2f(ushort u) {
  union { unsigned u; float f; } v; v.u = ((unsigned)u) << 16;
  return v.f;
}

// ---------------- graph preprocessing (atomic-free: LDS histograms) ----------------

// P1: per-(slice,chunk) histogram via LDS atomics -> partials[sl][node]
__global__ __launch_bounds__(256) void count_partial_kernel(
    const int4* __restrict__ keys4, unsigned* __restrict__ partials) {
  __shared__ unsigned cnt[CHK];
  const int chunk = blockIdx.x & 3;
  const int sl = blockIdx.x >> 2;
  for (int i = threadIdx.x; i < CHK; i += 256) cnt[i] = 0;
  __syncthreads();
  const int base4 = sl * (ESL / 4);
  const int lo = chunk * CHK;
  for (int i = threadIdx.x; i < ESL / 4; i += 256) {
    int4 k = keys4[base4 + i];
    int a;
    a = k.x - lo; if ((unsigned)a < (unsigned)CHK) atomicAdd(&cnt[a], 1u);
    a = k.y - lo; if ((unsigned)a < (unsigned)CHK) atomicAdd(&cnt[a], 1u);
    a = k.z - lo; if ((unsigned)a < (unsigned)CHK) atomicAdd(&cnt[a], 1u);
    a = k.w - lo; if ((unsigned)a < (unsigned)CHK) atomicAdd(&cnt[a], 1u);
  }
  __syncthreads();
  unsigned* p = partials + (long)sl * NN + lo;
  for (int i = threadIdx.x; i < CHK; i += 256) p[i] = cnt[i];
}

// P2: reduce partials -> indeg (for scan) + inverse-degree tables
__global__ __launch_bounds__(256) void reduce_deg_kernel(
    const unsigned* __restrict__ pd, const unsigned* __restrict__ ps,
    int* __restrict__ indeg, float* __restrict__ inv_mean,
    float* __restrict__ inv_in, float* __restrict__ inv_out) {
  int n = blockIdx.x * 256 + threadIdx.x;
  if (n >= NN) return;
  unsigned di = 0, dz = 0;
  #pragma unroll 8
  for (int sl = 0; sl < NSL; ++sl) {
    di += pd[(long)sl * NN + n];
    dz += ps[(long)sl * NN + n];
  }
  indeg[n] = (int)di;
  float fdi = fmaxf((float)di, 1.f), fdz = fmaxf((float)dz, 1.f);
  inv_mean[n] = 1.f / fdi;
  inv_in[n]  = rsqrtf(fdi);
  inv_out[n] = rsqrtf(fdz);
}

__global__ __launch_bounds__(256) void scan_block_kernel(const int* __restrict__ counts,
                                                         int* excl, int* bsum, int n) {
  __shared__ int sh[256];
  int i = blockIdx.x * 256 + threadIdx.x;
  int v = (i < n) ? counts[i] : 0;
  sh[threadIdx.x] = v;
  __syncthreads();
  #pragma unroll
  for (int off = 1; off < 256; off <<= 1) {
    int tv = (threadIdx.x >= off) ? sh[threadIdx.x - off] : 0;
    __syncthreads();
    sh[threadIdx.x] += tv;
    __syncthreads();
  }
  if (i < n) excl[i] = sh[threadIdx.x] - v;
  if (threadIdx.x == 255 && bsum) bsum[blockIdx.x] = sh[255];
}

// P3: finalize row_ptr (+block offsets) and per-(slice,node) starting cursors
__global__ void cursor_init_kernel(int* __restrict__ row_ptr, const int* __restrict__ bsum,
                                   const unsigned* __restrict__ pd,
                                   unsigned* __restrict__ cur0) {
  int n = blockIdx.x * 256 + threadIdx.x;
  if (n < NN) {
    unsigned run = (unsigned)(row_ptr[n] + bsum[n >> 8]);
    row_ptr[n] = (int)run;
    #pragma unroll 8
    for (int sl = 0; sl < NSL; ++sl) {
      cur0[(long)sl * NN + n] = run;
      run += pd[(long)sl * NN + n];
    }
  }
  if (n == NN) row_ptr[NN] = EE;
}

// P4: CSR scatter with LDS cursors (no global atomics)
__global__ __launch_bounds__(256) void fill_partial_kernel(
    const int4* __restrict__ dst4, const int4* __restrict__ src4,
    const unsigned* __restrict__ cur0, int* __restrict__ col) {
  __shared__ unsigned cur[CHK];
  const int chunk = blockIdx.x & 3;
  const int sl = blockIdx.x >> 2;
  const int lo = chunk * CHK;
  const unsigned* c0 = cur0 + (long)sl * NN + lo;
  for (int i = threadIdx.x; i < CHK; i += 256) cur[i] = c0[i];
  __syncthreads();
  const int base4 = sl * (ESL / 4);
  for (int i = threadIdx.x; i < ESL / 4; i += 256) {
    int4 d = dst4[base4 + i];
    int4 s = src4[base4 + i];
    int a;
    a = d.x - lo; if ((unsigned)a < (unsigned)CHK) col[atomicAdd(&cur[a], 1u)] = s.x;
    a = d.y - lo; if ((unsigned)a < (unsigned)CHK) col[atomicAdd(&cur[a], 1u)] = s.y;
    a = d.z - lo; if ((unsigned)a < (unsigned)CHK) col[atomicAdd(&cur[a], 1u)] = s.z;
    a = d.w - lo; if ((unsigned)a < (unsigned)CHK) col[atomicAdd(&cur[a], 1u)] = s.w;
  }
}

// ---------------- SpMM over feature-sliced fp16 table ----------------
// X16s layout: [slice=8][node][16] __half. block b: slice = b&7 (XCD-aligned),
// 4 waves = 4 nodes. Wave: lane = e8*8 + f2; 8 edges x 8 half2 per iteration.

__global__ __launch_bounds__(256) void spmm16s_kernel(
    const int* __restrict__ row_ptr, const int* __restrict__ cols,
    const __half2* __restrict__ xs, const float* __restrict__ dscale,
    float* __restrict__ out) {
  const int t = threadIdx.x;
  const int lane = t & 63;
  const int wv = t >> 6;
  const int b = blockIdx.x;
  const int slice = b & 7;
  const int node = (b >> 3) * 4 + wv;
  if (node >= NN) return;
  const __half2* xb = xs + (long)slice * NN * 8;
  const int e0 = row_ptr[node], end = row_ptr[node + 1];
  const int f2 = lane & 7;
  const int e8 = lane >> 3;
  float ax = 0.f, ay = 0.f;
  for (int e = e0; e < end; e += 8) {
    int ee = e + e8;
    if (ee < end) {
      int s = cols[ee];
      float2 f = __half22float2(xb[(long)s * 8 + f2]);
      ax += f.x; ay += f.y;
    }
  }
  ax += __shfl_xor(ax, 8, 64);  ay += __shfl_xor(ay, 8, 64);
  ax += __shfl_xor(ax, 16, 64); ay += __shfl_xor(ay, 16, 64);
  ax += __shfl_xor(ax, 32, 64); ay += __shfl_xor(ay, 32, 64);
  if (lane < 8) {
    float d = dscale[node];
    *(float2*)&out[(long)node * HF + slice * 16 + f2 * 2] = make_float2(ax * d, ay * d);
  }
}

// ---------------- attention gate + gated residual ----------------

__global__ __launch_bounds__(128) void attn_hatt_kernel(
    const float* a, const float* __restrict__ w2, const float* __restrict__ b2,
    const float* __restrict__ h0, const float* __restrict__ agg,
    const float* __restrict__ inv_out,
    float* hatt, __half* __restrict__ hatt16) {
  int r = blockIdx.x, f = threadIdx.x;
  long idx = (long)r * HF + f;
  float v = a[idx] * w2[f];
  #pragma unroll
  for (int off = 32; off >= 1; off >>= 1) v += __shfl_down(v, off, 64);
  __shared__ float red[2];
  if ((f & 63) == 0) red[f >> 6] = v;
  __syncthreads();
  float dot = red[0] + red[1] + b2[0];
  float s = 1.f / (1.f + __expf(-dot));
  float h = h0[idx] + agg[idx] * s;
  hatt[idx] = h;
  hatt16[((long)(f >> 4) * NN + r) * 16 + (f & 15)] = __float2half(h * inv_out[r]);
}

// ---------------- weight prepack: fp32 W[K][N] -> bf16 hi/lo MFMA fragments ----------------

__global__ void prepack_kernel(const float* __restrict__ W, int N, int ldw, int NTpad,
                               ushort* __restrict__ hi, ushort* __restrict__ lo, int total) {
  int idx = blockIdx.x * 256 + threadIdx.x;
  if (idx >= total) return;
  int j    = idx & 7;
  int lane = (idx >> 3) & 63;
  int rest = idx >> 9;
  int nt = rest % NTpad;
  int kc = rest / NTpad;
  int k = kc * 32 + (lane >> 4) * 8 + j;
  int n = nt * 16 + (lane & 15);
  float w = (n < N) ? W[(long)k * ldw + n] : 0.f;
  ushort h = f2bf(w);
  hi[idx] = h;
  lo[idx] = f2bf(w - bf2f(h));
}

// ---------------- split-bf16 MFMA GEMM: out = epi( [A1|A2] @ W + bias ) ----------------

template<int KC, int NT, int EPI, int H16>
__global__ __launch_bounds__(256) void mgemm_kernel(
    const float* __restrict__ A1, int lda1,
    const float* __restrict__ A2, int lda2,
    const ushort* __restrict__ Bhi, const ushort* __restrict__ Blo,
    const float* __restrict__ bias,
    const float* __restrict__ g, const float* __restrict__ be,
    const float* __restrict__ mu, const float* __restrict__ va,
    const float* __restrict__ res,
    float* __restrict__ out, int ldc, int Ncols,
    __half* __restrict__ out16, const float* __restrict__ rowscale) {
  const int t = threadIdx.x;
  const int lane = t & 63;
  const int wid = t >> 6;
  const int rowbase = blockIdx.x * 128 + wid * 32;
  const int arow0 = rowbase + (lane & 15);
  const int arow1 = arow0 + 16;
  const int kgrp = (lane >> 4) * 8;

  f32x4 acc[2][NT];
  #pragma unroll
  for (int r = 0; r < 2; ++r)
    #pragma unroll
    for (int n = 0; n < NT; ++n) acc[r][n] = (f32x4){0.f, 0.f, 0.f, 0.f};

  for (int kc = 0; kc < KC; ++kc) {
    const bool second = (KC == 8) && (kc >= 4);
    const float* Ap = second ? A2 : A1;
    const int lda = second ? lda2 : lda1;
    const long kb = (long)(second ? (kc - 4) * 32 : kc * 32) + kgrp;

    const f32x4 z4 = {0.f, 0.f, 0.f, 0.f};
    f32x4 av0a = z4, av0b = z4, av1a = z4, av1b = z4;
    if (arow0 < NN) {
      const float* p = Ap + (long)arow0 * lda + kb;
      av0a = *(const f32x4*)p;
      av0b = *(const f32x4*)(p + 4);
    }
    if (arow1 < NN) {
      const float* p = Ap + (long)arow1 * lda + kb;
      av1a = *(const f32x4*)p;
      av1b = *(const f32x4*)(p + 4);
    }

    bf16x8 ah0, al0, ah1, al1;
    #pragma unroll
    for (int j = 0; j < 8; ++j) {
      float v0 = (j < 4) ? av0a[j] : av0b[j - 4];
      ushort h0 = f2bf(v0);
      ah0[j] = (short)h0;
      al0[j] = (short)f2bf(v0 - bf2f(h0));
      float v1 = (j < 4) ? av1a[j] : av1b[j - 4];
      ushort h1 = f2bf(v1);
      ah1[j] = (short)h1;
      al1[j] = (short)f2bf(v1 - bf2f(h1));
    }

    const ushort* bh = Bhi + ((long)kc * NT * 64 + lane) * 8;
    const ushort* bl = Blo + ((long)kc * NT * 64 + lane) * 8;
    #pragma unroll
    for (int nt = 0; nt < NT; ++nt) {
      bf16x8 bhv = *(const bf16x8*)(bh + (long)nt * 512);
      bf16x8 blv = *(const bf16x8*)(bl + (long)nt * 512);
      acc[0][nt] = __builtin_amdgcn_mfma_f32_16x16x32_bf16(ah0, bhv, acc[0][nt], 0, 0, 0);
      acc[1][nt] = __builtin_amdgcn_mfma_f32_16x16x32_bf16(ah1, bhv, acc[1][nt], 0, 0, 0);
      acc[0][nt] = __builtin_amdgcn_mfma_f32_16x16x32_bf16(al0, bhv, acc[0][nt], 0, 0, 0);
      acc[1][nt] = __builtin_amdgcn_mfma_f32_16x16x32_bf16(al1, bhv, acc[1][nt], 0, 0, 0);
      acc[0][nt] = __builtin_amdgcn_mfma_f32_16x16x32_bf16(ah0, blv, acc[0][nt], 0, 0, 0);
      acc[1][nt] = __builtin_amdgcn_mfma_f32_16x16x32_bf16(ah1, blv, acc[1][nt], 0, 0, 0);
    }
  }

  const int colg = lane & 15;
  const int rsub = (lane >> 4) * 4;
  #pragma unroll
  for (int nt = 0; nt < NT; ++nt) {
    int c = nt * 16 + colg;
    if (c >= Ncols) continue;
    float bb = bias ? bias[c] : 0.f;
    float scale = 1.f, shift = 0.f;
    if (EPI == EPI_BN || EPI == EPI_BN_RES) {
      scale = g[c] * rsqrtf(va[c] + EPSV);
      shift = be[c] - mu[c] * scale;
    }
    #pragma unroll
    for (int rg = 0; rg < 2; ++rg) {
      #pragma unroll
      for (int i = 0; i < 4; ++i) {
        int r = rowbase + rg * 16 + rsub + i;
        if (r >= NN) continue;
        float v = acc[rg][nt][i] + bb;
        if (EPI == EPI_RELU) {
          v = fmaxf(v, 0.f);
        } else if (EPI == EPI_BN || EPI == EPI_BN_RES) {
          v = fmaxf(v * scale + shift, 0.f);
          if (EPI == EPI_BN_RES) v += res[(long)r * HF + c];
        }
        out[(long)r * ldc + c] = v;
        if (H16 != H16_NONE) {
          float sc = (H16 == H16_SCALED) ? rowscale[r] : 1.f;
          out16[((long)nt * NN + r) * 16 + colg] = __float2half(v * sc);
        }
      }
    }
  }
}

// ---------------- launch ----------------

extern "C" void kernel_launch(void* const* d_in, const int* in_sizes, int n_in,
                              void* d_out, int out_size, void* d_ws, size_t ws_size,
                              hipStream_t stream) {
  const float* features = (const float*)d_in[0];
  const int*   src      = (const int*)d_in[1];
  const int*   dst      = (const int*)d_in[2];
  const float* w_in     = (const float*)d_in[3];
  const float* b_in     = (const float*)d_in[4];
  const float* gc_w     = (const float*)d_in[5];
  const float* gc_b     = (const float*)d_in[6];
  const float* bn_gamma = (const float*)d_in[7];
  const float* bn_beta  = (const float*)d_in[8];
  const float* bn_mean  = (const float*)d_in[9];
  const float* bn_var   = (const float*)d_in[10];
  const float* attn_w1  = (const float*)d_in[11];
  const float* attn_b1  = (const float*)d_in[12];
  const float* attn_w2  = (const float*)d_in[13];
  const float* attn_b2  = (const float*)d_in[14];
  const float* agg_w    = (const float*)d_in[15];
  const float* agg_b    = (const float*)d_in[16];
  const float* out_w    = (const float*)d_in[17];
  const float* out_b    = (const float*)d_in[18];
  float* out = (float*)d_out;

  float* fbase   = (float*)d_ws;
  float* W0 = fbase;                 // h0 -> spmm scratch
  float* W1 = fbase + NH;            // neigh -> a -> h_att -> h(final)
  float* W2 = fbase + 2 * NH;        // agg -> h(L0) -> h(L2)
  float* inv_mean = fbase + 3 * NH;
  float* inv_in   = inv_mean + NN;
  float* inv_out  = inv_in + NN;
  int* indeg   = (int*)(inv_out + NN);
  int* row_ptr = indeg + NN;         // NN+1
  int* bsum    = row_ptr + NN + 1;   // 256
  int* col     = bsum + 256;         // EE

  // preprocessing scratch aliased into W1 (only used before W1's first write)
  unsigned* pd   = (unsigned*)W1;             // NSL*NN = 6.4MB
  unsigned* ps   = pd + (long)NSL * NN;       // 6.4MB
  unsigned* cur0 = ps + (long)NSL * NN;       // 6.4MB

  // packed bf16 hi/lo weights
  ushort* pk = (ushort*)(col + EE);
  const int SZ256 = 8 * 8 * 512;     // K=256, NT=8
  const int SZ128 = 4 * 8 * 512;     // K=128, NT=8
  const int SZOUT = 4 * 4 * 512;     // K=128, NT=4
  ushort* win_hi = pk;  pk += SZ256;  ushort* win_lo = pk;  pk += SZ256;
  ushort* agg_hi = pk;  pk += SZ256;  ushort* agg_lo = pk;  pk += SZ256;
  ushort* at1_hi = pk;  pk += SZ256;  ushort* at1_lo = pk;  pk += SZ256;
  ushort* gch[3], *gcl[3];
  for (int i = 0; i < 3; ++i) { gch[i] = pk; pk += SZ128; gcl[i] = pk; pk += SZ128; }
  ushort* ow_hi = pk;  pk += SZOUT;   ushort* ow_lo = pk;  pk += SZOUT;
  __half* X16 = (__half*)pk;          // NH halfs, sliced [8][NN][16]

  dim3 b256(256), b128(128);
  const int gN = (NN + 255) / 256;
  const int gblocks = (NN + 127) / 128;
  const int gspmm = ((NN + 3) / 4) * 8;
  const int gpre = NSL * 4;

  // graph preprocessing (no global atomics)
  count_partial_kernel<<<gpre, b256, 0, stream>>>((const int4*)dst, pd);
  count_partial_kernel<<<gpre, b256, 0, stream>>>((const int4*)src, ps);
  reduce_deg_kernel<<<gN, b256, 0, stream>>>(pd, ps, indeg, inv_mean, inv_in, inv_out);
  scan_block_kernel<<<gN, b256, 0, stream>>>(indeg, row_ptr, bsum, NN);
  scan_block_kernel<<<1, b256, 0, stream>>>(bsum, bsum, nullptr, gN);
  cursor_init_kernel<<<gN, b256, 0, stream>>>(row_ptr, bsum, pd, cur0);
  fill_partial_kernel<<<gpre, b256, 0, stream>>>((const int4*)dst, (const int4*)src, cur0, col);

  // weight prepack
  prepack_kernel<<<(SZ256 + 255) / 256, b256, 0, stream>>>(w_in,    HF, HF, 8, win_hi, win_lo, SZ256);
  prepack_kernel<<<(SZ256 + 255) / 256, b256, 0, stream>>>(agg_w,   HF, HF, 8, agg_hi, agg_lo, SZ256);
  prepack_kernel<<<(SZ256 + 255) / 256, b256, 0, stream>>>(attn_w1, HF, HF, 8, at1_hi, at1_lo, SZ256);
  for (int i = 0; i < 3; ++i)
    prepack_kernel<<<(SZ128 + 255) / 256, b256, 0, stream>>>(gc_w + (long)i * HF * HF, HF, HF, 8, gch[i], gcl[i], SZ128);
  prepack_kernel<<<(SZOUT + 255) / 256, b256, 0, stream>>>(out_w, CC, CC, 4, ow_hi, ow_lo, SZOUT);

  // h0 = relu(features @ w_in + b_in)            -> W0 (+fp16 raw sliced -> X16)
  mgemm_kernel<8, 8, EPI_RELU, H16_RAW><<<gblocks, b256, 0, stream>>>(
      features, INF_, features + 128, INF_, win_hi, win_lo, b_in,
      nullptr, nullptr, nullptr, nullptr, nullptr, W0, HF, HF, X16, nullptr);
  // neigh = mean-agg(h0)                          -> W1
  spmm16s_kernel<<<gspmm, b256, 0, stream>>>(row_ptr, col, (const __half2*)X16, inv_mean, W1);
  // agg = relu([h0|neigh] @ agg_w + agg_b)        -> W2
  mgemm_kernel<8, 8, EPI_RELU, H16_NONE><<<gblocks, b256, 0, stream>>>(
      W0, HF, W1, HF, agg_hi, agg_lo, agg_b,
      nullptr, nullptr, nullptr, nullptr, nullptr, W2, HF, HF, nullptr, nullptr);
  // a = relu([h0|agg] @ attn_w1 + attn_b1)        -> W1
  mgemm_kernel<8, 8, EPI_RELU, H16_NONE><<<gblocks, b256, 0, stream>>>(
      W0, HF, W2, HF, at1_hi, at1_lo, attn_b1,
      nullptr, nullptr, nullptr, nullptr, nullptr, W1, HF, HF, nullptr, nullptr);
  // h_att = h0 + agg * sigmoid(a@w2+b2)           -> W1 (+fp16 *inv_out sliced -> X16)
  attn_hatt_kernel<<<NN, b128, 0, stream>>>(W1, attn_w2, attn_b2, W0, W2, inv_out, W1, X16);

  // layer 0: spmm(X16)->W0 ; relu(BN(W0@gc0+b0))          -> W2 (+fp16 -> X16)
  spmm16s_kernel<<<gspmm, b256, 0, stream>>>(row_ptr, col, (const __half2*)X16, inv_in, W0);
  mgemm_kernel<4, 8, EPI_BN, H16_SCALED><<<gblocks, b256, 0, stream>>>(
      W0, HF, nullptr, 0, gch[0], gcl[0], gc_b,
      bn_gamma, bn_beta, bn_mean, bn_var, nullptr, W2, HF, HF, X16, inv_out);
  // layer 1: spmm(X16)->W0 ; relu(BN(W0@gc1+b1)) + W2     -> W1 (+fp16 -> X16)
  spmm16s_kernel<<<gspmm, b256, 0, stream>>>(row_ptr, col, (const __half2*)X16, inv_in, W0);
  mgemm_kernel<4, 8, EPI_BN_RES, H16_SCALED><<<gblocks, b256, 0, stream>>>(
      W0, HF, nullptr, 0, gch[1], gcl[1], gc_b + HF,
      bn_gamma + HF, bn_beta + HF, bn_mean + HF, bn_var + HF, W2, W1, HF, HF, X16, inv_out);
  // layer 2: spmm(X16)->W0 ; relu(BN(W0@gc2+b2)) + W1     -> W2
  spmm16s_kernel<<<gspmm, b256, 0, stream>>>(row_ptr, col, (const __half2*)X16, inv_in, W0);
  mgemm_kernel<4, 8, EPI_BN_RES, H16_NONE><<<gblocks, b256, 0, stream>>>(
      W0, HF, nullptr, 0, gch[2], gcl[2], gc_b + 2 * HF,
      bn_gamma + 2 * HF, bn_beta + 2 * HF, bn_mean + 2 * HF, bn_var + 2 * HF, W1, W2, HF, HF,
      nullptr, nullptr);

  // out = W2 @ out_w + out_b                      -> d_out
  mgemm_kernel<4, 4, EPI_NONE, H16_NONE><<<gblocks, b256, 0, stream>>>(
      W2, HF, nullptr, 0, ow_hi, ow_lo, out_b,
      nullptr, nullptr, nullptr, nullptr, nullptr, out, CC, CC, nullptr, nullptr);
}

// Round 6
// 677.051 us; speedup vs baseline: 1.1478x; 1.1478x over previous
//
#include <hip/hip_runtime.h>
#include <hip/hip_fp16.h>
#include <math.h>

constexpr int NN  = 50000;   // nodes
constexpr int EE  = 800000;  // edges
constexpr int INF_ = 256;    // input feat
constexpr int HF  = 128;     // hidden
constexpr int CC  = 50;      // classes
constexpr long NH = (long)NN * HF;
constexpr int NSL = 32;          // edge slices
constexpr int ESL = EE / NSL;    // 25000 edges per slice
constexpr int CHK = 12500;       // nodes per chunk (4 chunks), 50KB LDS
#define EPSV 1e-5f

enum { EPI_RELU = 0, EPI_NONE = 1, EPI_BN = 2, EPI_BN_RES = 3 };
enum { H16_NONE = 0, H16_RAW = 1, H16_SCALED = 2 };

typedef __attribute__((ext_vector_type(4))) float f32x4;
typedef __attribute__((ext_vector_type(8))) short bf16x8;

__device__ __forceinline__ ushort f2bf(float f) {
  union { float f; unsigned u; } v; v.f = f;
  unsigned r = (v.u + 0x7fffu + ((v.u >> 16) & 1u)) >> 16;  // RNE
  return (ushort)r;
}
__device__ __forceinline__ float bf2f(ushort u) {
  union { unsigned u; float f; } v; v.u = ((unsigned)u) << 16;
  return v.f;
}

// ---------------- graph preprocessing (atomic-free: LDS histograms) ----------------

__global__ __launch_bounds__(256) void count_partial_kernel(
    const int4* __restrict__ keys4, unsigned* __restrict__ partials) {
  __shared__ unsigned cnt[CHK];
  const int chunk = blockIdx.x & 3;
  const int sl = blockIdx.x >> 2;
  for (int i = threadIdx.x; i < CHK; i += 256) cnt[i] = 0;
  __syncthreads();
  const int base4 = sl * (ESL / 4);
  const int lo = chunk * CHK;
  for (int i = threadIdx.x; i < ESL / 4; i += 256) {
    int4 k = keys4[base4 + i];
    int a;
    a = k.x - lo; if ((unsigned)a < (unsigned)CHK) atomicAdd(&cnt[a], 1u);
    a = k.y - lo; if ((unsigned)a < (unsigned)CHK) atomicAdd(&cnt[a], 1u);
    a = k.z - lo; if ((unsigned)a < (unsigned)CHK) atomicAdd(&cnt[a], 1u);
    a = k.w - lo; if ((unsigned)a < (unsigned)CHK) atomicAdd(&cnt[a], 1u);
  }
  __syncthreads();
  unsigned* p = partials + (long)sl * NN + lo;
  for (int i = threadIdx.x; i < CHK; i += 256) p[i] = cnt[i];
}

__global__ __launch_bounds__(256) void reduce_deg_kernel(
    const unsigned* __restrict__ pd, const unsigned* __restrict__ ps,
    int* __restrict__ indeg, float* __restrict__ inv_mean,
    float* __restrict__ inv_in, float* __restrict__ inv_out) {
  int n = blockIdx.x * 256 + threadIdx.x;
  if (n >= NN) return;
  unsigned di = 0, dz = 0;
  #pragma unroll 8
  for (int sl = 0; sl < NSL; ++sl) {
    di += pd[(long)sl * NN + n];
    dz += ps[(long)sl * NN + n];
  }
  indeg[n] = (int)di;
  float fdi = fmaxf((float)di, 1.f), fdz = fmaxf((float)dz, 1.f);
  inv_mean[n] = 1.f / fdi;
  inv_in[n]  = rsqrtf(fdi);
  inv_out[n] = rsqrtf(fdz);
}

__global__ __launch_bounds__(256) void scan_block_kernel(const int* __restrict__ counts,
                                                         int* excl, int* bsum, int n) {
  __shared__ int sh[256];
  int i = blockIdx.x * 256 + threadIdx.x;
  int v = (i < n) ? counts[i] : 0;
  sh[threadIdx.x] = v;
  __syncthreads();
  #pragma unroll
  for (int off = 1; off < 256; off <<= 1) {
    int tv = (threadIdx.x >= off) ? sh[threadIdx.x - off] : 0;
    __syncthreads();
    sh[threadIdx.x] += tv;
    __syncthreads();
  }
  if (i < n) excl[i] = sh[threadIdx.x] - v;
  if (threadIdx.x == 255 && bsum) bsum[blockIdx.x] = sh[255];
}

__global__ void cursor_init_kernel(int* __restrict__ row_ptr, const int* __restrict__ bsum,
                                   const unsigned* __restrict__ pd,
                                   unsigned* __restrict__ cur0) {
  int n = blockIdx.x * 256 + threadIdx.x;
  if (n < NN) {
    unsigned run = (unsigned)(row_ptr[n] + bsum[n >> 8]);
    row_ptr[n] = (int)run;
    #pragma unroll 8
    for (int sl = 0; sl < NSL; ++sl) {
      cur0[(long)sl * NN + n] = run;
      run += pd[(long)sl * NN + n];
    }
  }
  if (n == NN) row_ptr[NN] = EE;
}

__global__ __launch_bounds__(256) void fill_partial_kernel(
    const int4* __restrict__ dst4, const int4* __restrict__ src4,
    const unsigned* __restrict__ cur0, int* __restrict__ col) {
  __shared__ unsigned cur[CHK];
  const int chunk = blockIdx.x & 3;
  const int sl = blockIdx.x >> 2;
  const int lo = chunk * CHK;
  const unsigned* c0 = cur0 + (long)sl * NN + lo;
  for (int i = threadIdx.x; i < CHK; i += 256) cur[i] = c0[i];
  __syncthreads();
  const int base4 = sl * (ESL / 4);
  for (int i = threadIdx.x; i < ESL / 4; i += 256) {
    int4 d = dst4[base4 + i];
    int4 s = src4[base4 + i];
    int a;
    a = d.x - lo; if ((unsigned)a < (unsigned)CHK) col[atomicAdd(&cur[a], 1u)] = s.x;
    a = d.y - lo; if ((unsigned)a < (unsigned)CHK) col[atomicAdd(&cur[a], 1u)] = s.y;
    a = d.z - lo; if ((unsigned)a < (unsigned)CHK) col[atomicAdd(&cur[a], 1u)] = s.z;
    a = d.w - lo; if ((unsigned)a < (unsigned)CHK) col[atomicAdd(&cur[a], 1u)] = s.w;
  }
}

// ---------------- SpMM over feature-sliced fp16 table ----------------
// X16s layout: [slice=8][node][16] __half. block b: slice = b&7 (XCD-aligned),
// 4 waves = 4 nodes. Wave: lane = e8*8 + f2. Unroll x4 with clamp+mask:
// loads are unconditional (safe: end>e0 inside loop), 4 gathers in flight.

__global__ __launch_bounds__(256) void spmm16s_kernel(
    const int* __restrict__ row_ptr, const int* __restrict__ cols,
    const __half2* __restrict__ xs, const float* __restrict__ dscale,
    float* __restrict__ out) {
  const int t = threadIdx.x;
  const int lane = t & 63;
  const int wv = t >> 6;
  const int b = blockIdx.x;
  const int slice = b & 7;
  const int node = (b >> 3) * 4 + wv;
  if (node >= NN) return;
  const __half2* xb = xs + (long)slice * NN * 8;
  const int e0 = row_ptr[node], end = row_ptr[node + 1];
  const int f2 = lane & 7;
  const int e8 = lane >> 3;
  float ax = 0.f, ay = 0.f;
  for (int e = e0; e < end; e += 32) {
    #pragma unroll
    for (int u = 0; u < 4; ++u) {
      int ee = e + u * 8 + e8;
      int ec = (ee < end) ? ee : (end - 1);   // clamp: load always valid
      int s = cols[ec];
      float2 f = __half22float2(xb[(unsigned)s * 8u + f2]);
      bool m = ee < end;
      ax += m ? f.x : 0.f;
      ay += m ? f.y : 0.f;
    }
  }
  ax += __shfl_xor(ax, 8, 64);  ay += __shfl_xor(ay, 8, 64);
  ax += __shfl_xor(ax, 16, 64); ay += __shfl_xor(ay, 16, 64);
  ax += __shfl_xor(ax, 32, 64); ay += __shfl_xor(ay, 32, 64);
  if (lane < 8) {
    float d = dscale[node];
    *(float2*)&out[(long)node * HF + slice * 16 + f2 * 2] = make_float2(ax * d, ay * d);
  }
}

// ---------------- attention gate + gated residual ----------------

__global__ __launch_bounds__(128) void attn_hatt_kernel(
    const float* a, const float* __restrict__ w2, const float* __restrict__ b2,
    const float* __restrict__ h0, const float* __restrict__ agg,
    const float* __restrict__ inv_out,
    float* hatt, __half* __restrict__ hatt16) {
  int r = blockIdx.x, f = threadIdx.x;
  long idx = (long)r * HF + f;
  float v = a[idx] * w2[f];
  #pragma unroll
  for (int off = 32; off >= 1; off >>= 1) v += __shfl_down(v, off, 64);
  __shared__ float red[2];
  if ((f & 63) == 0) red[f >> 6] = v;
  __syncthreads();
  float dot = red[0] + red[1] + b2[0];
  float s = 1.f / (1.f + __expf(-dot));
  float h = h0[idx] + agg[idx] * s;
  hatt[idx] = h;
  hatt16[((long)(f >> 4) * NN + r) * 16 + (f & 15)] = __float2half(h * inv_out[r]);
}

// ---------------- weight prepack: fp32 W[K][N] -> bf16 hi/lo MFMA fragments ----------------

__global__ void prepack_kernel(const float* __restrict__ W, int N, int ldw, int NTpad,
                               ushort* __restrict__ hi, ushort* __restrict__ lo, int total) {
  int idx = blockIdx.x * 256 + threadIdx.x;
  if (idx >= total) return;
  int j    = idx & 7;
  int lane = (idx >> 3) & 63;
  int rest = idx >> 9;
  int nt = rest % NTpad;
  int kc = rest / NTpad;
  int k = kc * 32 + (lane >> 4) * 8 + j;
  int n = nt * 16 + (lane & 15);
  float w = (n < N) ? W[(long)k * ldw + n] : 0.f;
  ushort h = f2bf(w);
  hi[idx] = h;
  lo[idx] = f2bf(w - bf2f(h));
}

// ---------------- split-bf16 MFMA GEMM: out = epi( [A1|A2] @ W + bias ) ----------------

template<int KC, int NT, int EPI, int H16>
__global__ __launch_bounds__(256) void mgemm_kernel(
    const float* __restrict__ A1, int lda1,
    const float* __restrict__ A2, int lda2,
    const ushort* __restrict__ Bhi, const ushort* __restrict__ Blo,
    const float* __restrict__ bias,
    const float* __restrict__ g, const float* __restrict__ be,
    const float* __restrict__ mu, const float* __restrict__ va,
    const float* __restrict__ res,
    float* __restrict__ out, int ldc, int Ncols,
    __half* __restrict__ out16, const float* __restrict__ rowscale) {
  const int t = threadIdx.x;
  const int lane = t & 63;
  const int wid = t >> 6;
  const int rowbase = blockIdx.x * 128 + wid * 32;
  const int arow0 = rowbase + (lane & 15);
  const int arow1 = arow0 + 16;
  const int kgrp = (lane >> 4) * 8;

  f32x4 acc[2][NT];
  #pragma unroll
  for (int r = 0; r < 2; ++r)
    #pragma unroll
    for (int n = 0; n < NT; ++n) acc[r][n] = (f32x4){0.f, 0.f, 0.f, 0.f};

  for (int kc = 0; kc < KC; ++kc) {
    const bool second = (KC == 8) && (kc >= 4);
    const float* Ap = second ? A2 : A1;
    const int lda = second ? lda2 : lda1;
    const long kb = (long)(second ? (kc - 4) * 32 : kc * 32) + kgrp;

    const f32x4 z4 = {0.f, 0.f, 0.f, 0.f};
    f32x4 av0a = z4, av0b = z4, av1a = z4, av1b = z4;
    if (arow0 < NN) {
      const float* p = Ap + (long)arow0 * lda + kb;
      av0a = *(const f32x4*)p;
      av0b = *(const f32x4*)(p + 4);
    }
    if (arow1 < NN) {
      const float* p = Ap + (long)arow1 * lda + kb;
      av1a = *(const f32x4*)p;
      av1b = *(const f32x4*)(p + 4);
    }

    bf16x8 ah0, al0, ah1, al1;
    #pragma unroll
    for (int j = 0; j < 8; ++j) {
      float v0 = (j < 4) ? av0a[j] : av0b[j - 4];
      ushort h0 = f2bf(v0);
      ah0[j] = (short)h0;
      al0[j] = (short)f2bf(v0 - bf2f(h0));
      float v1 = (j < 4) ? av1a[j] : av1b[j - 4];
      ushort h1 = f2bf(v1);
      ah1[j] = (short)h1;
      al1[j] = (short)f2bf(v1 - bf2f(h1));
    }

    const ushort* bh = Bhi + ((long)kc * NT * 64 + lane) * 8;
    const ushort* bl = Blo + ((long)kc * NT * 64 + lane) * 8;
    #pragma unroll
    for (int nt = 0; nt < NT; ++nt) {
      bf16x8 bhv = *(const bf16x8*)(bh + (long)nt * 512);
      bf16x8 blv = *(const bf16x8*)(bl + (long)nt * 512);
      acc[0][nt] = __builtin_amdgcn_mfma_f32_16x16x32_bf16(ah0, bhv, acc[0][nt], 0, 0, 0);
      acc[1][nt] = __builtin_amdgcn_mfma_f32_16x16x32_bf16(ah1, bhv, acc[1][nt], 0, 0, 0);
      acc[0][nt] = __builtin_amdgcn_mfma_f32_16x16x32_bf16(al0, bhv, acc[0][nt], 0, 0, 0);
      acc[1][nt] = __builtin_amdgcn_mfma_f32_16x16x32_bf16(al1, bhv, acc[1][nt], 0, 0, 0);
      acc[0][nt] = __builtin_amdgcn_mfma_f32_16x16x32_bf16(ah0, blv, acc[0][nt], 0, 0, 0);
      acc[1][nt] = __builtin_amdgcn_mfma_f32_16x16x32_bf16(ah1, blv, acc[1][nt], 0, 0, 0);
    }
  }

  const int colg = lane & 15;
  const int rsub = (lane >> 4) * 4;
  #pragma unroll
  for (int nt = 0; nt < NT; ++nt) {
    int c = nt * 16 + colg;
    if (c >= Ncols) continue;
    float bb = bias ? bias[c] : 0.f;
    float scale = 1.f, shift = 0.f;
    if (EPI == EPI_BN || EPI == EPI_BN_RES) {
      scale = g[c] * rsqrtf(va[c] + EPSV);
      shift = be[c] - mu[c] * scale;
    }
    #pragma unroll
    for (int rg = 0; rg < 2; ++rg) {
      #pragma unroll
      for (int i = 0; i < 4; ++i) {
        int r = rowbase + rg * 16 + rsub + i;
        if (r >= NN) continue;
        float v = acc[rg][nt][i] + bb;
        if (EPI == EPI_RELU) {
          v = fmaxf(v, 0.f);
        } else if (EPI == EPI_BN || EPI == EPI_BN_RES) {
          v = fmaxf(v * scale + shift, 0.f);
          if (EPI == EPI_BN_RES) v += res[(long)r * HF + c];
        }
        out[(long)r * ldc + c] = v;
        if (H16 != H16_NONE) {
          float sc = (H16 == H16_SCALED) ? rowscale[r] : 1.f;
          out16[((long)nt * NN + r) * 16 + colg] = __float2half(v * sc);
        }
      }
    }
  }
}

// ---------------- launch ----------------

extern "C" void kernel_launch(void* const* d_in, const int* in_sizes, int n_in,
                              void* d_out, int out_size, void* d_ws, size_t ws_size,
                              hipStream_t stream) {
  const float* features = (const float*)d_in[0];
  const int*   src      = (const int*)d_in[1];
  const int*   dst      = (const int*)d_in[2];
  const float* w_in     = (const float*)d_in[3];
  const float* b_in     = (const float*)d_in[4];
  const float* gc_w     = (const float*)d_in[5];
  const float* gc_b     = (const float*)d_in[6];
  const float* bn_gamma = (const float*)d_in[7];
  const float* bn_beta  = (const float*)d_in[8];
  const float* bn_mean  = (const float*)d_in[9];
  const float* bn_var   = (const float*)d_in[10];
  const float* attn_w1  = (const float*)d_in[11];
  const float* attn_b1  = (const float*)d_in[12];
  const float* attn_w2  = (const float*)d_in[13];
  const float* attn_b2  = (const float*)d_in[14];
  const float* agg_w    = (const float*)d_in[15];
  const float* agg_b    = (const float*)d_in[16];
  const float* out_w    = (const float*)d_in[17];
  const float* out_b    = (const float*)d_in[18];
  float* out = (float*)d_out;

  float* fbase   = (float*)d_ws;
  float* W0 = fbase;                 // h0 -> spmm scratch
  float* W1 = fbase + NH;            // neigh -> a -> h_att -> h(final)
  float* W2 = fbase + 2 * NH;        // agg -> h(L0) -> h(L2)
  float* inv_mean = fbase + 3 * NH;
  float* inv_in   = inv_mean + NN;
  float* inv_out  = inv_in + NN;
  int* indeg   = (int*)(inv_out + NN);
  int* row_ptr = indeg + NN;         // NN+1
  int* bsum    = row_ptr + NN + 1;   // 256
  int* col     = bsum + 256;         // EE

  // preprocessing scratch aliased into W1 (only used before W1's first write)
  unsigned* pd   = (unsigned*)W1;             // NSL*NN = 6.4MB
  unsigned* ps   = pd + (long)NSL * NN;       // 6.4MB
  unsigned* cur0 = ps + (long)NSL * NN;       // 6.4MB

  // packed bf16 hi/lo weights
  ushort* pk = (ushort*)(col + EE);
  const int SZ256 = 8 * 8 * 512;     // K=256, NT=8
  const int SZ128 = 4 * 8 * 512;     // K=128, NT=8
  const int SZOUT = 4 * 4 * 512;     // K=128, NT=4
  ushort* win_hi = pk;  pk += SZ256;  ushort* win_lo = pk;  pk += SZ256;
  ushort* agg_hi = pk;  pk += SZ256;  ushort* agg_lo = pk;  pk += SZ256;
  ushort* at1_hi = pk;  pk += SZ256;  ushort* at1_lo = pk;  pk += SZ256;
  ushort* gch[3], *gcl[3];
  for (int i = 0; i < 3; ++i) { gch[i] = pk; pk += SZ128; gcl[i] = pk; pk += SZ128; }
  ushort* ow_hi = pk;  pk += SZOUT;   ushort* ow_lo = pk;  pk += SZOUT;
  __half* X16 = (__half*)pk;          // NH halfs, sliced [8][NN][16]

  dim3 b256(256), b128(128);
  const int gN = (NN + 255) / 256;
  const int gblocks = (NN + 127) / 128;
  const int gspmm = ((NN + 3) / 4) * 8;
  const int gpre = NSL * 4;

  // graph preprocessing (no global atomics)
  count_partial_kernel<<<gpre, b256, 0, stream>>>((const int4*)dst, pd);
  count_partial_kernel<<<gpre, b256, 0, stream>>>((const int4*)src, ps);
  reduce_deg_kernel<<<gN, b256, 0, stream>>>(pd, ps, indeg, inv_mean, inv_in, inv_out);
  scan_block_kernel<<<gN, b256, 0, stream>>>(indeg, row_ptr, bsum, NN);
  scan_block_kernel<<<1, b256, 0, stream>>>(bsum, bsum, nullptr, gN);
  cursor_init_kernel<<<gN, b256, 0, stream>>>(row_ptr, bsum, pd, cur0);
  fill_partial_kernel<<<gpre, b256, 0, stream>>>((const int4*)dst, (const int4*)src, cur0, col);

  // weight prepack
  prepack_kernel<<<(SZ256 + 255) / 256, b256, 0, stream>>>(w_in,    HF, HF, 8, win_hi, win_lo, SZ256);
  prepack_kernel<<<(SZ256 + 255) / 256, b256, 0, stream>>>(agg_w,   HF, HF, 8, agg_hi, agg_lo, SZ256);
  prepack_kernel<<<(SZ256 + 255) / 256, b256, 0, stream>>>(attn_w1, HF, HF, 8, at1_hi, at1_lo, SZ256);
  for (int i = 0; i < 3; ++i)
    prepack_kernel<<<(SZ128 + 255) / 256, b256, 0, stream>>>(gc_w + (long)i * HF * HF, HF, HF, 8, gch[i], gcl[i], SZ128);
  prepack_kernel<<<(SZOUT + 255) / 256, b256, 0, stream>>>(out_w, CC, CC, 4, ow_hi, ow_lo, SZOUT);

  // h0 = relu(features @ w_in + b_in)            -> W0 (+fp16 raw sliced -> X16)
  mgemm_kernel<8, 8, EPI_RELU, H16_RAW><<<gblocks, b256, 0, stream>>>(
      features, INF_, features + 128, INF_, win_hi, win_lo, b_in,
      nullptr, nullptr, nullptr, nullptr, nullptr, W0, HF, HF, X16, nullptr);
  // neigh = mean-agg(h0)                          -> W1
  spmm16s_kernel<<<gspmm, b256, 0, stream>>>(row_ptr, col, (const __half2*)X16, inv_mean, W1);
  // agg = relu([h0|neigh] @ agg_w + agg_b)        -> W2
  mgemm_kernel<8, 8, EPI_RELU, H16_NONE><<<gblocks, b256, 0, stream>>>(
      W0, HF, W1, HF, agg_hi, agg_lo, agg_b,
      nullptr, nullptr, nullptr, nullptr, nullptr, W2, HF, HF, nullptr, nullptr);
  // a = relu([h0|agg] @ attn_w1 + attn_b1)        -> W1
  mgemm_kernel<8, 8, EPI_RELU, H16_NONE><<<gblocks, b256, 0, stream>>>(
      W0, HF, W2, HF, at1_hi, at1_lo, attn_b1,
      nullptr, nullptr, nullptr, nullptr, nullptr, W1, HF, HF, nullptr, nullptr);
  // h_att = h0 + agg * sigmoid(a@w2+b2)           -> W1 (+fp16 *inv_out sliced -> X16)
  attn_hatt_kernel<<<NN, b128, 0, stream>>>(W1, attn_w2, attn_b2, W0, W2, inv_out, W1, X16);

  // layer 0: spmm(X16)->W0 ; relu(BN(W0@gc0+b0))          -> W2 (+fp16 -> X16)
  spmm16s_kernel<<<gspmm, b256, 0, stream>>>(row_ptr, col, (const __half2*)X16, inv_in, W0);
  mgemm_kernel<4, 8, EPI_BN, H16_SCALED><<<gblocks, b256, 0, stream>>>(
      W0, HF, nullptr, 0, gch[0], gcl[0], gc_b,
      bn_gamma, bn_beta, bn_mean, bn_var, nullptr, W2, HF, HF, X16, inv_out);
  // layer 1: spmm(X16)->W0 ; relu(BN(W0@gc1+b1)) + W2     -> W1 (+fp16 -> X16)
  spmm16s_kernel<<<gspmm, b256, 0, stream>>>(row_ptr, col, (const __half2*)X16, inv_in, W0);
  mgemm_kernel<4, 8, EPI_BN_RES, H16_SCALED><<<gblocks, b256, 0, stream>>>(
      W0, HF, nullptr, 0, gch[1], gcl[1], gc_b + HF,
      bn_gamma + HF, bn_beta + HF, bn_mean + HF, bn_var + HF, W2, W1, HF, HF, X16, inv_out);
  // layer 2: spmm(X16)->W0 ; relu(BN(W0@gc2+b2)) + W1     -> W2
  spmm16s_kernel<<<gspmm, b256, 0, stream>>>(row_ptr, col, (const __half2*)X16, inv_in, W0);
  mgemm_kernel<4, 8, EPI_BN_RES, H16_NONE><<<gblocks, b256, 0, stream>>>(
      W0, HF, nullptr, 0, gch[2], gcl[2], gc_b + 2 * HF,
      bn_gamma + 2 * HF, bn_beta + 2 * HF, bn_mean + 2 * HF, bn_var + 2 * HF, W1, W2, HF, HF,
      nullptr, nullptr);

  // out = W2 @ out_w + out_b                      -> d_out
  mgemm_kernel<4, 4, EPI_NONE, H16_NONE><<<gblocks, b256, 0, stream>>>(
      W2, HF, nullptr, 0, ow_hi, ow_lo, out_b,
      nullptr, nullptr, nullptr, nullptr, nullptr, out, CC, CC, nullptr, nullptr);
}

// Round 7
// 607.887 us; speedup vs baseline: 1.2784x; 1.1138x over previous
//
#include <hip/hip_runtime.h>
#include <hip/hip_fp16.h>
#include <math.h>

constexpr int NN  = 50000;   // nodes
constexpr int EE  = 800000;  // edges
constexpr int INF_ = 256;    // input feat
constexpr int HF  = 128;     // hidden
constexpr int CC  = 50;      // classes
constexpr long NH = (long)NN * HF;
constexpr int NSL = 32;          // edge slices (preprocessing)
constexpr int ESL = EE / NSL;    // 25000 edges per slice
constexpr int CHK = 12500;       // nodes per chunk (4 chunks), 50KB LDS
#define EPSV 1e-5f

enum { EPI_RELU = 0, EPI_NONE = 1, EPI_BN = 2, EPI_BN_RES = 3 };
enum { H16_NONE = 0, H16_RAW = 1, H16_SCALED = 2 };

typedef __attribute__((ext_vector_type(4))) float f32x4;
typedef __attribute__((ext_vector_type(8))) short bf16x8;

__device__ __forceinline__ ushort f2bf(float f) {
  union { float f; unsigned u; } v; v.f = f;
  unsigned r = (v.u + 0x7fffu + ((v.u >> 16) & 1u)) >> 16;  // RNE
  return (ushort)r;
}
__device__ __forceinline__ float bf2f(ushort u) {
  union { unsigned u; float f; } v; v.u = ((unsigned)u) << 16;
  return v.f;
}

// ---------------- graph preprocessing (atomic-free: LDS histograms) ----------------

__global__ __launch_bounds__(256) void count_partial_kernel(
    const int4* __restrict__ keys4, unsigned* __restrict__ partials) {
  __shared__ unsigned cnt[CHK];
  const int chunk = blockIdx.x & 3;
  const int sl = blockIdx.x >> 2;
  for (int i = threadIdx.x; i < CHK; i += 256) cnt[i] = 0;
  __syncthreads();
  const int base4 = sl * (ESL / 4);
  const int lo = chunk * CHK;
  for (int i = threadIdx.x; i < ESL / 4; i += 256) {
    int4 k = keys4[base4 + i];
    int a;
    a = k.x - lo; if ((unsigned)a < (unsigned)CHK) atomicAdd(&cnt[a], 1u);
    a = k.y - lo; if ((unsigned)a < (unsigned)CHK) atomicAdd(&cnt[a], 1u);
    a = k.z - lo; if ((unsigned)a < (unsigned)CHK) atomicAdd(&cnt[a], 1u);
    a = k.w - lo; if ((unsigned)a < (unsigned)CHK) atomicAdd(&cnt[a], 1u);
  }
  __syncthreads();
  unsigned* p = partials + (long)sl * NN + lo;
  for (int i = threadIdx.x; i < CHK; i += 256) p[i] = cnt[i];
}

__global__ __launch_bounds__(256) void reduce_deg_kernel(
    const unsigned* __restrict__ pd, const unsigned* __restrict__ ps,
    int* __restrict__ indeg, float* __restrict__ inv_mean,
    float* __restrict__ inv_in, float* __restrict__ inv_out) {
  int n = blockIdx.x * 256 + threadIdx.x;
  if (n >= NN) return;
  unsigned di = 0, dz = 0;
  #pragma unroll 8
  for (int sl = 0; sl < NSL; ++sl) {
    di += pd[(long)sl * NN + n];
    dz += ps[(long)sl * NN + n];
  }
  indeg[n] = (int)di;
  float fdi = fmaxf((float)di, 1.f), fdz = fmaxf((float)dz, 1.f);
  inv_mean[n] = 1.f / fdi;
  inv_in[n]  = rsqrtf(fdi);
  inv_out[n] = rsqrtf(fdz);
}

__global__ __launch_bounds__(256) void scan_block_kernel(const int* __restrict__ counts,
                                                         int* excl, int* bsum, int n) {
  __shared__ int sh[256];
  int i = blockIdx.x * 256 + threadIdx.x;
  int v = (i < n) ? counts[i] : 0;
  sh[threadIdx.x] = v;
  __syncthreads();
  #pragma unroll
  for (int off = 1; off < 256; off <<= 1) {
    int tv = (threadIdx.x >= off) ? sh[threadIdx.x - off] : 0;
    __syncthreads();
    sh[threadIdx.x] += tv;
    __syncthreads();
  }
  if (i < n) excl[i] = sh[threadIdx.x] - v;
  if (threadIdx.x == 255 && bsum) bsum[blockIdx.x] = sh[255];
}

__global__ void cursor_init_kernel(int* __restrict__ row_ptr, const int* __restrict__ bsum,
                                   const unsigned* __restrict__ pd,
                                   unsigned* __restrict__ cur0) {
  int n = blockIdx.x * 256 + threadIdx.x;
  if (n < NN) {
    unsigned run = (unsigned)(row_ptr[n] + bsum[n >> 8]);
    row_ptr[n] = (int)run;
    #pragma unroll 8
    for (int sl = 0; sl < NSL; ++sl) {
      cur0[(long)sl * NN + n] = run;
      run += pd[(long)sl * NN + n];
    }
  }
  if (n == NN) row_ptr[NN] = EE;
}

__global__ __launch_bounds__(256) void fill_partial_kernel(
    const int4* __restrict__ dst4, const int4* __restrict__ src4,
    const unsigned* __restrict__ cur0, int* __restrict__ col) {
  __shared__ unsigned cur[CHK];
  const int chunk = blockIdx.x & 3;
  const int sl = blockIdx.x >> 2;
  const int lo = chunk * CHK;
  const unsigned* c0 = cur0 + (long)sl * NN + lo;
  for (int i = threadIdx.x; i < CHK; i += 256) cur[i] = c0[i];
  __syncthreads();
  const int base4 = sl * (ESL / 4);
  for (int i = threadIdx.x; i < ESL / 4; i += 256) {
    int4 d = dst4[base4 + i];
    int4 s = src4[base4 + i];
    int a;
    a = d.x - lo; if ((unsigned)a < (unsigned)CHK) col[atomicAdd(&cur[a], 1u)] = s.x;
    a = d.y - lo; if ((unsigned)a < (unsigned)CHK) col[atomicAdd(&cur[a], 1u)] = s.y;
    a = d.z - lo; if ((unsigned)a < (unsigned)CHK) col[atomicAdd(&cur[a], 1u)] = s.z;
    a = d.w - lo; if ((unsigned)a < (unsigned)CHK) col[atomicAdd(&cur[a], 1u)] = s.w;
  }
}

// ---------------- SpMM over feature-sliced fp16 table (32-feat slices) ----------------
// X16 layout: [slice=4][node][32] __half (64B rows, 3.2MB/slice -> L2-resident,
// slice pinned to XCD-pair via blockIdx&7). Wave = one (node, slice);
// lane = q4*16 + e16: one dwordx4 load gathers 16 edges x full 64B row.

__global__ __launch_bounds__(256) void spmm32s_kernel(
    const int* __restrict__ row_ptr, const int* __restrict__ cols,
    const __half* __restrict__ xs, const float* __restrict__ dscale,
    float* __restrict__ out) {
  const int t = threadIdx.x;
  const int lane = t & 63;
  const int wv = t >> 6;
  const int b = blockIdx.x;
  const int xcd = b & 7;
  const int slice = xcd >> 1;
  const int sub = xcd & 1;
  const int node = (b >> 3) * 8 + wv * 2 + sub;   // exact cover: NN = 6250*8
  const int e16 = lane & 15;
  const int q4 = lane >> 4;
  const __half* xb = xs + (long)slice * NN * 32;
  const int e0 = row_ptr[node], end = row_ptr[node + 1];
  const int end1 = end - 1;
  float a0 = 0.f, a1 = 0.f, a2 = 0.f, a3 = 0.f, a4 = 0.f, a5 = 0.f, a6 = 0.f, a7 = 0.f;
  for (int e = e0; e < end; e += 32) {
    {
      int ee = e + e16;
      int ec = ee < end ? ee : end1;
      int s = cols[ec];
      float msk = ee < end ? 1.f : 0.f;
      f32x4 rv = *(const f32x4*)(xb + (unsigned)s * 32u + q4 * 8);
      const __half2* hp = (const __half2*)&rv;
      float2 f0 = __half22float2(hp[0]), f1 = __half22float2(hp[1]);
      float2 f2 = __half22float2(hp[2]), f3 = __half22float2(hp[3]);
      a0 = fmaf(f0.x, msk, a0); a1 = fmaf(f0.y, msk, a1);
      a2 = fmaf(f1.x, msk, a2); a3 = fmaf(f1.y, msk, a3);
      a4 = fmaf(f2.x, msk, a4); a5 = fmaf(f2.y, msk, a5);
      a6 = fmaf(f3.x, msk, a6); a7 = fmaf(f3.y, msk, a7);
    }
    if (e + 16 < end) {   // wave-uniform branch
      int ee = e + 16 + e16;
      int ec = ee < end ? ee : end1;
      int s = cols[ec];
      float msk = ee < end ? 1.f : 0.f;
      f32x4 rv = *(const f32x4*)(xb + (unsigned)s * 32u + q4 * 8);
      const __half2* hp = (const __half2*)&rv;
      float2 f0 = __half22float2(hp[0]), f1 = __half22float2(hp[1]);
      float2 f2 = __half22float2(hp[2]), f3 = __half22float2(hp[3]);
      a0 = fmaf(f0.x, msk, a0); a1 = fmaf(f0.y, msk, a1);
      a2 = fmaf(f1.x, msk, a2); a3 = fmaf(f1.y, msk, a3);
      a4 = fmaf(f2.x, msk, a4); a5 = fmaf(f2.y, msk, a5);
      a6 = fmaf(f3.x, msk, a6); a7 = fmaf(f3.y, msk, a7);
    }
  }
  #pragma unroll
  for (int m = 1; m < 16; m <<= 1) {
    a0 += __shfl_xor(a0, m, 64); a1 += __shfl_xor(a1, m, 64);
    a2 += __shfl_xor(a2, m, 64); a3 += __shfl_xor(a3, m, 64);
    a4 += __shfl_xor(a4, m, 64); a5 += __shfl_xor(a5, m, 64);
    a6 += __shfl_xor(a6, m, 64); a7 += __shfl_xor(a7, m, 64);
  }
  if (e16 == 0) {
    float d = dscale[node];
    float* op = out + (long)node * HF + slice * 32 + q4 * 8;
    *(f32x4*)op       = (f32x4){a0 * d, a1 * d, a2 * d, a3 * d};
    *(f32x4*)(op + 4) = (f32x4){a4 * d, a5 * d, a6 * d, a7 * d};
  }
}

// ---------------- attention gate + gated residual ----------------

__global__ __launch_bounds__(128) void attn_hatt_kernel(
    const float* a, const float* __restrict__ w2, const float* __restrict__ b2,
    const float* __restrict__ h0, const float* __restrict__ agg,
    const float* __restrict__ inv_out,
    float* hatt, __half* __restrict__ hatt16) {
  int r = blockIdx.x, f = threadIdx.x;
  long idx = (long)r * HF + f;
  float v = a[idx] * w2[f];
  #pragma unroll
  for (int off = 32; off >= 1; off >>= 1) v += __shfl_down(v, off, 64);
  __shared__ float red[2];
  if ((f & 63) == 0) red[f >> 6] = v;
  __syncthreads();
  float dot = red[0] + red[1] + b2[0];
  float s = 1.f / (1.f + __expf(-dot));
  float h = h0[idx] + agg[idx] * s;
  hatt[idx] = h;
  hatt16[((long)(f >> 5) * NN + r) * 32 + (f & 31)] = __float2half(h * inv_out[r]);
}

// ---------------- weight prepack: fp32 W[K][N] -> bf16 hi/lo MFMA fragments ----------------

__global__ void prepack_kernel(const float* __restrict__ W, int N, int ldw, int NTpad,
                               ushort* __restrict__ hi, ushort* __restrict__ lo, int total) {
  int idx = blockIdx.x * 256 + threadIdx.x;
  if (idx >= total) return;
  int j    = idx & 7;
  int lane = (idx >> 3) & 63;
  int rest = idx >> 9;
  int nt = rest % NTpad;
  int kc = rest / NTpad;
  int k = kc * 32 + (lane >> 4) * 8 + j;
  int n = nt * 16 + (lane & 15);
  float w = (n < N) ? W[(long)k * ldw + n] : 0.f;
  ushort h = f2bf(w);
  hi[idx] = h;
  lo[idx] = f2bf(w - bf2f(h));
}

// ---------------- split-bf16 MFMA GEMM: out = epi( [A1|A2] @ W + bias ) ----------------

template<int KC, int NT, int EPI, int H16>
__global__ __launch_bounds__(256) void mgemm_kernel(
    const float* __restrict__ A1, int lda1,
    const float* __restrict__ A2, int lda2,
    const ushort* __restrict__ Bhi, const ushort* __restrict__ Blo,
    const float* __restrict__ bias,
    const float* __restrict__ g, const float* __restrict__ be,
    const float* __restrict__ mu, const float* __restrict__ va,
    const float* __restrict__ res,
    float* __restrict__ out, int ldc, int Ncols,
    __half* __restrict__ out16, const float* __restrict__ rowscale) {
  const int t = threadIdx.x;
  const int lane = t & 63;
  const int wid = t >> 6;
  const int rowbase = blockIdx.x * 128 + wid * 32;
  const int arow0 = rowbase + (lane & 15);
  const int arow1 = arow0 + 16;
  const int kgrp = (lane >> 4) * 8;

  f32x4 acc[2][NT];
  #pragma unroll
  for (int r = 0; r < 2; ++r)
    #pragma unroll
    for (int n = 0; n < NT; ++n) acc[r][n] = (f32x4){0.f, 0.f, 0.f, 0.f};

  for (int kc = 0; kc < KC; ++kc) {
    const bool second = (KC == 8) && (kc >= 4);
    const float* Ap = second ? A2 : A1;
    const int lda = second ? lda2 : lda1;
    const long kb = (long)(second ? (kc - 4) * 32 : kc * 32) + kgrp;

    const f32x4 z4 = {0.f, 0.f, 0.f, 0.f};
    f32x4 av0a = z4, av0b = z4, av1a = z4, av1b = z4;
    if (arow0 < NN) {
      const float* p = A1 == Ap ? Ap + (long)arow0 * lda + kb : Ap + (long)arow0 * lda + kb;
      av0a = *(const f32x4*)p;
      av0b = *(const f32x4*)(p + 4);
    }
    if (arow1 < NN) {
      const float* p = Ap + (long)arow1 * lda + kb;
      av1a = *(const f32x4*)p;
      av1b = *(const f32x4*)(p + 4);
    }

    bf16x8 ah0, al0, ah1, al1;
    #pragma unroll
    for (int j = 0; j < 8; ++j) {
      float v0 = (j < 4) ? av0a[j] : av0b[j - 4];
      ushort h0 = f2bf(v0);
      ah0[j] = (short)h0;
      al0[j] = (short)f2bf(v0 - bf2f(h0));
      float v1 = (j < 4) ? av1a[j] : av1b[j - 4];
      ushort h1 = f2bf(v1);
      ah1[j] = (short)h1;
      al1[j] = (short)f2bf(v1 - bf2f(h1));
    }

    const ushort* bh = Bhi + ((long)kc * NT * 64 + lane) * 8;
    const ushort* bl = Blo + ((long)kc * NT * 64 + lane) * 8;
    #pragma unroll
    for (int nt = 0; nt < NT; ++nt) {
      bf16x8 bhv = *(const bf16x8*)(bh + (long)nt * 512);
      bf16x8 blv = *(const bf16x8*)(bl + (long)nt * 512);
      acc[0][nt] = __builtin_amdgcn_mfma_f32_16x16x32_bf16(ah0, bhv, acc[0][nt], 0, 0, 0);
      acc[1][nt] = __builtin_amdgcn_mfma_f32_16x16x32_bf16(ah1, bhv, acc[1][nt], 0, 0, 0);
      acc[0][nt] = __builtin_amdgcn_mfma_f32_16x16x32_bf16(al0, bhv, acc[0][nt], 0, 0, 0);
      acc[1][nt] = __builtin_amdgcn_mfma_f32_16x16x32_bf16(al1, bhv, acc[1][nt], 0, 0, 0);
      acc[0][nt] = __builtin_amdgcn_mfma_f32_16x16x32_bf16(ah0, blv, acc[0][nt], 0, 0, 0);
      acc[1][nt] = __builtin_amdgcn_mfma_f32_16x16x32_bf16(ah1, blv, acc[1][nt], 0, 0, 0);
    }
  }

  const int colg = lane & 15;
  const int rsub = (lane >> 4) * 4;
  #pragma unroll
  for (int nt = 0; nt < NT; ++nt) {
    int c = nt * 16 + colg;
    if (c >= Ncols) continue;
    float bb = bias ? bias[c] : 0.f;
    float scale = 1.f, shift = 0.f;
    if (EPI == EPI_BN || EPI == EPI_BN_RES) {
      scale = g[c] * rsqrtf(va[c] + EPSV);
      shift = be[c] - mu[c] * scale;
    }
    #pragma unroll
    for (int rg = 0; rg < 2; ++rg) {
      #pragma unroll
      for (int i = 0; i < 4; ++i) {
        int r = rowbase + rg * 16 + rsub + i;
        if (r >= NN) continue;
        float v = acc[rg][nt][i] + bb;
        if (EPI == EPI_RELU) {
          v = fmaxf(v, 0.f);
        } else if (EPI == EPI_BN || EPI == EPI_BN_RES) {
          v = fmaxf(v * scale + shift, 0.f);
          if (EPI == EPI_BN_RES) v += res[(long)r * HF + c];
        }
        out[(long)r * ldc + c] = v;
        if (H16 != H16_NONE) {
          float sc = (H16 == H16_SCALED) ? rowscale[r] : 1.f;
          out16[((long)(nt >> 1) * NN + r) * 32 + (nt & 1) * 16 + colg] = __float2half(v * sc);
        }
      }
    }
  }
}

// ---------------- launch ----------------

extern "C" void kernel_launch(void* const* d_in, const int* in_sizes, int n_in,
                              void* d_out, int out_size, void* d_ws, size_t ws_size,
                              hipStream_t stream) {
  const float* features = (const float*)d_in[0];
  const int*   src      = (const int*)d_in[1];
  const int*   dst      = (const int*)d_in[2];
  const float* w_in     = (const float*)d_in[3];
  const float* b_in     = (const float*)d_in[4];
  const float* gc_w     = (const float*)d_in[5];
  const float* gc_b     = (const float*)d_in[6];
  const float* bn_gamma = (const float*)d_in[7];
  const float* bn_beta  = (const float*)d_in[8];
  const float* bn_mean  = (const float*)d_in[9];
  const float* bn_var   = (const float*)d_in[10];
  const float* attn_w1  = (const float*)d_in[11];
  const float* attn_b1  = (const float*)d_in[12];
  const float* attn_w2  = (const float*)d_in[13];
  const float* attn_b2  = (const float*)d_in[14];
  const float* agg_w    = (const float*)d_in[15];
  const float* agg_b    = (const float*)d_in[16];
  const float* out_w    = (const float*)d_in[17];
  const float* out_b    = (const float*)d_in[18];
  float* out = (float*)d_out;

  float* fbase   = (float*)d_ws;
  float* W0 = fbase;                 // h0 -> spmm scratch
  float* W1 = fbase + NH;            // neigh -> a -> h_att -> h(final)
  float* W2 = fbase + 2 * NH;        // agg -> h(L0) -> h(L2)
  float* inv_mean = fbase + 3 * NH;
  float* inv_in   = inv_mean + NN;
  float* inv_out  = inv_in + NN;
  int* indeg   = (int*)(inv_out + NN);
  int* row_ptr = indeg + NN;         // NN+1
  int* bsum    = row_ptr + NN + 1;   // 256
  int* col     = bsum + 256;         // EE

  // preprocessing scratch aliased into W1 (only used before W1's first write)
  unsigned* pd   = (unsigned*)W1;             // NSL*NN = 6.4MB
  unsigned* ps   = pd + (long)NSL * NN;       // 6.4MB
  unsigned* cur0 = ps + (long)NSL * NN;       // 6.4MB

  // packed bf16 hi/lo weights
  ushort* pk = (ushort*)(col + EE);
  const int SZ256 = 8 * 8 * 512;     // K=256, NT=8
  const int SZ128 = 4 * 8 * 512;     // K=128, NT=8
  const int SZOUT = 4 * 4 * 512;     // K=128, NT=4
  ushort* win_hi = pk;  pk += SZ256;  ushort* win_lo = pk;  pk += SZ256;
  ushort* agg_hi = pk;  pk += SZ256;  ushort* agg_lo = pk;  pk += SZ256;
  ushort* at1_hi = pk;  pk += SZ256;  ushort* at1_lo = pk;  pk += SZ256;
  ushort* gch[3], *gcl[3];
  for (int i = 0; i < 3; ++i) { gch[i] = pk; pk += SZ128; gcl[i] = pk; pk += SZ128; }
  ushort* ow_hi = pk;  pk += SZOUT;   ushort* ow_lo = pk;  pk += SZOUT;
  __half* X16 = (__half*)pk;          // NH halfs, sliced [4][NN][32]

  dim3 b256(256), b128(128);
  const int gN = (NN + 255) / 256;
  const int gblocks = (NN + 127) / 128;
  const int gspmm = (NN / 8) * 8;     // 50000 blocks: (node-group)*8 + xcd
  const int gpre = NSL * 4;

  // graph preprocessing (no global atomics)
  count_partial_kernel<<<gpre, b256, 0, stream>>>((const int4*)dst, pd);
  count_partial_kernel<<<gpre, b256, 0, stream>>>((const int4*)src, ps);
  reduce_deg_kernel<<<gN, b256, 0, stream>>>(pd, ps, indeg, inv_mean, inv_in, inv_out);
  scan_block_kernel<<<gN, b256, 0, stream>>>(indeg, row_ptr, bsum, NN);
  scan_block_kernel<<<1, b256, 0, stream>>>(bsum, bsum, nullptr, gN);
  cursor_init_kernel<<<gN, b256, 0, stream>>>(row_ptr, bsum, pd, cur0);
  fill_partial_kernel<<<gpre, b256, 0, stream>>>((const int4*)dst, (const int4*)src, cur0, col);

  // weight prepack
  prepack_kernel<<<(SZ256 + 255) / 256, b256, 0, stream>>>(w_in,    HF, HF, 8, win_hi, win_lo, SZ256);
  prepack_kernel<<<(SZ256 + 255) / 256, b256, 0, stream>>>(agg_w,   HF, HF, 8, agg_hi, agg_lo, SZ256);
  prepack_kernel<<<(SZ256 + 255) / 256, b256, 0, stream>>>(attn_w1, HF, HF, 8, at1_hi, at1_lo, SZ256);
  for (int i = 0; i < 3; ++i)
    prepack_kernel<<<(SZ128 + 255) / 256, b256, 0, stream>>>(gc_w + (long)i * HF * HF, HF, HF, 8, gch[i], gcl[i], SZ128);
  prepack_kernel<<<(SZOUT + 255) / 256, b256, 0, stream>>>(out_w, CC, CC, 4, ow_hi, ow_lo, SZOUT);

  // h0 = relu(features @ w_in + b_in)            -> W0 (+fp16 raw sliced -> X16)
  mgemm_kernel<8, 8, EPI_RELU, H16_RAW><<<gblocks, b256, 0, stream>>>(
      features, INF_, features + 128, INF_, win_hi, win_lo, b_in,
      nullptr, nullptr, nullptr, nullptr, nullptr, W0, HF, HF, X16, nullptr);
  // neigh = mean-agg(h0)                          -> W1
  spmm32s_kernel<<<gspmm, b256, 0, stream>>>(row_ptr, col, X16, inv_mean, W1);
  // agg = relu([h0|neigh] @ agg_w + agg_b)        -> W2
  mgemm_kernel<8, 8, EPI_RELU, H16_NONE><<<gblocks, b256, 0, stream>>>(
      W0, HF, W1, HF, agg_hi, agg_lo, agg_b,
      nullptr, nullptr, nullptr, nullptr, nullptr, W2, HF, HF, nullptr, nullptr);
  // a = relu([h0|agg] @ attn_w1 + attn_b1)        -> W1
  mgemm_kernel<8, 8, EPI_RELU, H16_NONE><<<gblocks, b256, 0, stream>>>(
      W0, HF, W2, HF, at1_hi, at1_lo, attn_b1,
      nullptr, nullptr, nullptr, nullptr, nullptr, W1, HF, HF, nullptr, nullptr);
  // h_att = h0 + agg * sigmoid(a@w2+b2)           -> W1 (+fp16 *inv_out sliced -> X16)
  attn_hatt_kernel<<<NN, b128, 0, stream>>>(W1, attn_w2, attn_b2, W0, W2, inv_out, W1, X16);

  // layer 0: spmm(X16)->W0 ; relu(BN(W0@gc0+b0))          -> W2 (+fp16 -> X16)
  spmm32s_kernel<<<gspmm, b256, 0, stream>>>(row_ptr, col, X16, inv_in, W0);
  mgemm_kernel<4, 8, EPI_BN, H16_SCALED><<<gblocks, b256, 0, stream>>>(
      W0, HF, nullptr, 0, gch[0], gcl[0], gc_b,
      bn_gamma, bn_beta, bn_mean, bn_var, nullptr, W2, HF, HF, X16, inv_out);
  // layer 1: spmm(X16)->W0 ; relu(BN(W0@gc1+b1)) + W2     -> W1 (+fp16 -> X16)
  spmm32s_kernel<<<gspmm, b256, 0, stream>>>(row_ptr, col, X16, inv_in, W0);
  mgemm_kernel<4, 8, EPI_BN_RES, H16_SCALED><<<gblocks, b256, 0, stream>>>(
      W0, HF, nullptr, 0, gch[1], gcl[1], gc_b + HF,
      bn_gamma + HF, bn_beta + HF, bn_mean + HF, bn_var + HF, W2, W1, HF, HF, X16, inv_out);
  // layer 2: spmm(X16)->W0 ; relu(BN(W0@gc2+b2)) + W1     -> W2
  spmm32s_kernel<<<gspmm, b256, 0, stream>>>(row_ptr, col, X16, inv_in, W0);
  mgemm_kernel<4, 8, EPI_BN_RES, H16_NONE><<<gblocks, b256, 0, stream>>>(
      W0, HF, nullptr, 0, gch[2], gcl[2], gc_b + 2 * HF,
      bn_gamma + 2 * HF, bn_beta + 2 * HF, bn_mean + 2 * HF, bn_var + 2 * HF, W1, W2, HF, HF,
      nullptr, nullptr);

  // out = W2 @ out_w + out_b                      -> d_out
  mgemm_kernel<4, 4, EPI_NONE, H16_NONE><<<gblocks, b256, 0, stream>>>(
      W2, HF, nullptr, 0, ow_hi, ow_lo, out_b,
      nullptr, nullptr, nullptr, nullptr, nullptr, out, CC, CC, nullptr, nullptr);
}

// Round 8
// 544.767 us; speedup vs baseline: 1.4266x; 1.1159x over previous
//
#include <hip/hip_runtime.h>
#include <hip/hip_fp16.h>
#include <math.h>

constexpr int NN  = 50000;   // nodes
constexpr int EE  = 800000;  // edges
constexpr int INF_ = 256;    // input feat
constexpr int HF  = 128;     // hidden
constexpr int CC  = 50;      // classes
constexpr long NH = (long)NN * HF;
constexpr int NSL = 32;          // edge slices (preprocessing)
constexpr int ESL = EE / NSL;    // 25000 edges per slice
constexpr int CHK = 12500;       // nodes per chunk (4 chunks), 50KB LDS
#define EPSV 1e-5f

enum { EPI_RELU = 0, EPI_NONE = 1, EPI_BN = 2, EPI_BN_RES = 3 };
enum { H16_NONE = 0, H16_RAW = 1, H16_SCALED = 2 };

typedef __attribute__((ext_vector_type(4))) float f32x4;
typedef __attribute__((ext_vector_type(8))) short bf16x8;

__device__ __forceinline__ ushort f2bf(float f) {
  union { float f; unsigned u; } v; v.f = f;
  unsigned r = (v.u + 0x7fffu + ((v.u >> 16) & 1u)) >> 16;  // RNE
  return (ushort)r;
}
__device__ __forceinline__ float bf2f(ushort u) {
  union { unsigned u; float f; } v; v.u = ((unsigned)u) << 16;
  return v.f;
}

// ---------------- graph preprocessing (atomic-free: LDS histograms) ----------------

__global__ __launch_bounds__(256) void count_partial_kernel(
    const int4* __restrict__ keys4, unsigned* __restrict__ partials) {
  __shared__ unsigned cnt[CHK];
  const int chunk = blockIdx.x & 3;
  const int sl = blockIdx.x >> 2;
  for (int i = threadIdx.x; i < CHK; i += 256) cnt[i] = 0;
  __syncthreads();
  const int base4 = sl * (ESL / 4);
  const int lo = chunk * CHK;
  for (int i = threadIdx.x; i < ESL / 4; i += 256) {
    int4 k = keys4[base4 + i];
    int a;
    a = k.x - lo; if ((unsigned)a < (unsigned)CHK) atomicAdd(&cnt[a], 1u);
    a = k.y - lo; if ((unsigned)a < (unsigned)CHK) atomicAdd(&cnt[a], 1u);
    a = k.z - lo; if ((unsigned)a < (unsigned)CHK) atomicAdd(&cnt[a], 1u);
    a = k.w - lo; if ((unsigned)a < (unsigned)CHK) atomicAdd(&cnt[a], 1u);
  }
  __syncthreads();
  unsigned* p = partials + (long)sl * NN + lo;
  for (int i = threadIdx.x; i < CHK; i += 256) p[i] = cnt[i];
}

__global__ __launch_bounds__(256) void reduce_deg_kernel(
    const unsigned* __restrict__ pd, const unsigned* __restrict__ ps,
    int* __restrict__ indeg, float* __restrict__ inv_mean,
    float* __restrict__ inv_in, float* __restrict__ inv_out) {
  int n = blockIdx.x * 256 + threadIdx.x;
  if (n >= NN) return;
  unsigned di = 0, dz = 0;
  #pragma unroll 8
  for (int sl = 0; sl < NSL; ++sl) {
    di += pd[(long)sl * NN + n];
    dz += ps[(long)sl * NN + n];
  }
  indeg[n] = (int)di;
  float fdi = fmaxf((float)di, 1.f), fdz = fmaxf((float)dz, 1.f);
  inv_mean[n] = 1.f / fdi;
  inv_in[n]  = rsqrtf(fdi);
  inv_out[n] = rsqrtf(fdz);
}

__global__ __launch_bounds__(256) void scan_block_kernel(const int* __restrict__ counts,
                                                         int* excl, int* bsum, int n) {
  __shared__ int sh[256];
  int i = blockIdx.x * 256 + threadIdx.x;
  int v = (i < n) ? counts[i] : 0;
  sh[threadIdx.x] = v;
  __syncthreads();
  #pragma unroll
  for (int off = 1; off < 256; off <<= 1) {
    int tv = (threadIdx.x >= off) ? sh[threadIdx.x - off] : 0;
    __syncthreads();
    sh[threadIdx.x] += tv;
    __syncthreads();
  }
  if (i < n) excl[i] = sh[threadIdx.x] - v;
  if (threadIdx.x == 255 && bsum) bsum[blockIdx.x] = sh[255];
}

__global__ void cursor_init_kernel(int* __restrict__ row_ptr, const int* __restrict__ bsum,
                                   const unsigned* __restrict__ pd,
                                   unsigned* __restrict__ cur0) {
  int n = blockIdx.x * 256 + threadIdx.x;
  if (n < NN) {
    unsigned run = (unsigned)(row_ptr[n] + bsum[n >> 8]);
    row_ptr[n] = (int)run;
    #pragma unroll 8
    for (int sl = 0; sl < NSL; ++sl) {
      cur0[(long)sl * NN + n] = run;
      run += pd[(long)sl * NN + n];
    }
  }
  if (n == NN) row_ptr[NN] = EE;
}

__global__ __launch_bounds__(256) void fill_partial_kernel(
    const int4* __restrict__ dst4, const int4* __restrict__ src4,
    const unsigned* __restrict__ cur0, int* __restrict__ col) {
  __shared__ unsigned cur[CHK];
  const int chunk = blockIdx.x & 3;
  const int sl = blockIdx.x >> 2;
  const int lo = chunk * CHK;
  const unsigned* c0 = cur0 + (long)sl * NN + lo;
  for (int i = threadIdx.x; i < CHK; i += 256) cur[i] = c0[i];
  __syncthreads();
  const int base4 = sl * (ESL / 4);
  for (int i = threadIdx.x; i < ESL / 4; i += 256) {
    int4 d = dst4[base4 + i];
    int4 s = src4[base4 + i];
    int a;
    a = d.x - lo; if ((unsigned)a < (unsigned)CHK) col[atomicAdd(&cur[a], 1u)] = s.x;
    a = d.y - lo; if ((unsigned)a < (unsigned)CHK) col[atomicAdd(&cur[a], 1u)] = s.y;
    a = d.z - lo; if ((unsigned)a < (unsigned)CHK) col[atomicAdd(&cur[a], 1u)] = s.z;
    a = d.w - lo; if ((unsigned)a < (unsigned)CHK) col[atomicAdd(&cur[a], 1u)] = s.w;
  }
}

// ---------------- SpMM over feature-sliced fp16 table (32-feat slices) ----------------
// X16 layout: [slice=4][node][32] __half (64B rows, 3.2MB/slice -> L2-resident,
// slice pinned to XCD-pair via blockIdx&7). Wave = one (node, slice);
// lane = e8*8 + q8: 8 edges x 8B (row covered by 8 consecutive lanes -> one
// 64B transaction per edge). 16 edges/iter via two independent 8-edge halves
// (2 cols + 2 gathers in flight). Reduce: 3-level xor tree x 4 accs only.

__global__ __launch_bounds__(256) void spmm32s_kernel(
    const int* __restrict__ row_ptr, const int* __restrict__ cols,
    const __half* __restrict__ xs, const float* __restrict__ dscale,
    float* __restrict__ out) {
  const int t = threadIdx.x;
  const int lane = t & 63;
  const int wv = t >> 6;
  const int b = blockIdx.x;
  const int xcd = b & 7;
  const int slice = xcd >> 1;
  const int sub = xcd & 1;
  const int node = (b >> 3) * 8 + wv * 2 + sub;   // exact cover: NN = 6250*8
  const int q8 = lane & 7;       // feature quarter: 4 halfs (8B)
  const int e8 = lane >> 3;      // edge slot within group of 8
  const __half* xb = xs + (long)slice * NN * 32 + q8 * 4;
  const int e0 = row_ptr[node], end = row_ptr[node + 1];
  const int end1 = end - 1;
  const float d = dscale[node];
  float a0 = 0.f, a1 = 0.f, a2 = 0.f, a3 = 0.f;
  float c0 = 0.f, c1 = 0.f, c2 = 0.f, c3 = 0.f;
  for (int e = e0; e < end; e += 16) {
    int ee0 = e + e8;
    int ee1 = ee0 + 8;
    int ec0 = ee0 < end ? ee0 : end1;
    int ec1 = ee1 < end ? ee1 : end1;
    int s0 = cols[ec0];
    int s1 = cols[ec1];
    float m0 = ee0 < end ? 1.f : 0.f;
    float m1 = ee1 < end ? 1.f : 0.f;
    float2 v0 = *(const float2*)(xb + (unsigned)s0 * 32u);
    float2 v1 = *(const float2*)(xb + (unsigned)s1 * 32u);
    const __half2* h0 = (const __half2*)&v0;
    const __half2* h1 = (const __half2*)&v1;
    float2 f00 = __half22float2(h0[0]), f01 = __half22float2(h0[1]);
    float2 f10 = __half22float2(h1[0]), f11 = __half22float2(h1[1]);
    a0 = fmaf(f00.x, m0, a0); a1 = fmaf(f00.y, m0, a1);
    a2 = fmaf(f01.x, m0, a2); a3 = fmaf(f01.y, m0, a3);
    c0 = fmaf(f10.x, m1, c0); c1 = fmaf(f10.y, m1, c1);
    c2 = fmaf(f11.x, m1, c2); c3 = fmaf(f11.y, m1, c3);
  }
  a0 += c0; a1 += c1; a2 += c2; a3 += c3;
  #pragma unroll
  for (int m = 8; m < 64; m <<= 1) {
    a0 += __shfl_xor(a0, m, 64);
    a1 += __shfl_xor(a1, m, 64);
    a2 += __shfl_xor(a2, m, 64);
    a3 += __shfl_xor(a3, m, 64);
  }
  if (lane < 8) {
    float* op = out + (long)node * HF + slice * 32 + q8 * 4;
    *(f32x4*)op = (f32x4){a0 * d, a1 * d, a2 * d, a3 * d};
  }
}

// ---------------- attention gate + gated residual ----------------

__global__ __launch_bounds__(128) void attn_hatt_kernel(
    const float* a, const float* __restrict__ w2, const float* __restrict__ b2,
    const float* __restrict__ h0, const float* __restrict__ agg,
    const float* __restrict__ inv_out,
    float* hatt, __half* __restrict__ hatt16) {
  int r = blockIdx.x, f = threadIdx.x;
  long idx = (long)r * HF + f;
  float v = a[idx] * w2[f];
  #pragma unroll
  for (int off = 32; off >= 1; off >>= 1) v += __shfl_down(v, off, 64);
  __shared__ float red[2];
  if ((f & 63) == 0) red[f >> 6] = v;
  __syncthreads();
  float dot = red[0] + red[1] + b2[0];
  float s = 1.f / (1.f + __expf(-dot));
  float h = h0[idx] + agg[idx] * s;
  hatt[idx] = h;
  hatt16[((long)(f >> 5) * NN + r) * 32 + (f & 31)] = __float2half(h * inv_out[r]);
}

// ---------------- weight prepack: fp32 W[K][N] -> bf16 hi/lo MFMA fragments ----------------

__global__ void prepack_kernel(const float* __restrict__ W, int N, int ldw, int NTpad,
                               ushort* __restrict__ hi, ushort* __restrict__ lo, int total) {
  int idx = blockIdx.x * 256 + threadIdx.x;
  if (idx >= total) return;
  int j    = idx & 7;
  int lane = (idx >> 3) & 63;
  int rest = idx >> 9;
  int nt = rest % NTpad;
  int kc = rest / NTpad;
  int k = kc * 32 + (lane >> 4) * 8 + j;
  int n = nt * 16 + (lane & 15);
  float w = (n < N) ? W[(long)k * ldw + n] : 0.f;
  ushort h = f2bf(w);
  hi[idx] = h;
  lo[idx] = f2bf(w - bf2f(h));
}

// ---------------- split-bf16 MFMA GEMM: out = epi( [A1|A2] @ W + bias ) ----------------

template<int KC, int NT, int EPI, int H16>
__global__ __launch_bounds__(256) void mgemm_kernel(
    const float* __restrict__ A1, int lda1,
    const float* __restrict__ A2, int lda2,
    const ushort* __restrict__ Bhi, const ushort* __restrict__ Blo,
    const float* __restrict__ bias,
    const float* __restrict__ g, const float* __restrict__ be,
    const float* __restrict__ mu, const float* __restrict__ va,
    const float* __restrict__ res,
    float* __restrict__ out, int ldc, int Ncols,
    __half* __restrict__ out16, const float* __restrict__ rowscale) {
  const int t = threadIdx.x;
  const int lane = t & 63;
  const int wid = t >> 6;
  const int rowbase = blockIdx.x * 128 + wid * 32;
  const int arow0 = rowbase + (lane & 15);
  const int arow1 = arow0 + 16;
  const int kgrp = (lane >> 4) * 8;

  f32x4 acc[2][NT];
  #pragma unroll
  for (int r = 0; r < 2; ++r)
    #pragma unroll
    for (int n = 0; n < NT; ++n) acc[r][n] = (f32x4){0.f, 0.f, 0.f, 0.f};

  for (int kc = 0; kc < KC; ++kc) {
    const bool second = (KC == 8) && (kc >= 4);
    const float* Ap = second ? A2 : A1;
    const int lda = second ? lda2 : lda1;
    const long kb = (long)(second ? (kc - 4) * 32 : kc * 32) + kgrp;

    const f32x4 z4 = {0.f, 0.f, 0.f, 0.f};
    f32x4 av0a = z4, av0b = z4, av1a = z4, av1b = z4;
    if (arow0 < NN) {
      const float* p = Ap + (long)arow0 * lda + kb;
      av0a = *(const f32x4*)p;
      av0b = *(const f32x4*)(p + 4);
    }
    if (arow1 < NN) {
      const float* p = Ap + (long)arow1 * lda + kb;
      av1a = *(const f32x4*)p;
      av1b = *(const f32x4*)(p + 4);
    }

    bf16x8 ah0, al0, ah1, al1;
    #pragma unroll
    for (int j = 0; j < 8; ++j) {
      float v0 = (j < 4) ? av0a[j] : av0b[j - 4];
      ushort h0 = f2bf(v0);
      ah0[j] = (short)h0;
      al0[j] = (short)f2bf(v0 - bf2f(h0));
      float v1 = (j < 4) ? av1a[j] : av1b[j - 4];
      ushort h1 = f2bf(v1);
      ah1[j] = (short)h1;
      al1[j] = (short)f2bf(v1 - bf2f(h1));
    }

    const ushort* bh = Bhi + ((long)kc * NT * 64 + lane) * 8;
    const ushort* bl = Blo + ((long)kc * NT * 64 + lane) * 8;
    #pragma unroll
    for (int nt = 0; nt < NT; ++nt) {
      bf16x8 bhv = *(const bf16x8*)(bh + (long)nt * 512);
      bf16x8 blv = *(const bf16x8*)(bl + (long)nt * 512);
      acc[0][nt] = __builtin_amdgcn_mfma_f32_16x16x32_bf16(ah0, bhv, acc[0][nt], 0, 0, 0);
      acc[1][nt] = __builtin_amdgcn_mfma_f32_16x16x32_bf16(ah1, bhv, acc[1][nt], 0, 0, 0);
      acc[0][nt] = __builtin_amdgcn_mfma_f32_16x16x32_bf16(al0, bhv, acc[0][nt], 0, 0, 0);
      acc[1][nt] = __builtin_amdgcn_mfma_f32_16x16x32_bf16(al1, bhv, acc[1][nt], 0, 0, 0);
      acc[0][nt] = __builtin_amdgcn_mfma_f32_16x16x32_bf16(ah0, blv, acc[0][nt], 0, 0, 0);
      acc[1][nt] = __builtin_amdgcn_mfma_f32_16x16x32_bf16(ah1, blv, acc[1][nt], 0, 0, 0);
    }
  }

  const int colg = lane & 15;
  const int rsub = (lane >> 4) * 4;
  #pragma unroll
  for (int nt = 0; nt < NT; ++nt) {
    int c = nt * 16 + colg;
    if (c >= Ncols) continue;
    float bb = bias ? bias[c] : 0.f;
    float scale = 1.f, shift = 0.f;
    if (EPI == EPI_BN || EPI == EPI_BN_RES) {
      scale = g[c] * rsqrtf(va[c] + EPSV);
      shift = be[c] - mu[c] * scale;
    }
    #pragma unroll
    for (int rg = 0; rg < 2; ++rg) {
      #pragma unroll
      for (int i = 0; i < 4; ++i) {
        int r = rowbase + rg * 16 + rsub + i;
        if (r >= NN) continue;
        float v = acc[rg][nt][i] + bb;
        if (EPI == EPI_RELU) {
          v = fmaxf(v, 0.f);
        } else if (EPI == EPI_BN || EPI == EPI_BN_RES) {
          v = fmaxf(v * scale + shift, 0.f);
          if (EPI == EPI_BN_RES) v += res[(long)r * HF + c];
        }
        out[(long)r * ldc + c] = v;
        if (H16 != H16_NONE) {
          float sc = (H16 == H16_SCALED) ? rowscale[r] : 1.f;
          out16[((long)(nt >> 1) * NN + r) * 32 + (nt & 1) * 16 + colg] = __float2half(v * sc);
        }
      }
    }
  }
}

// ---------------- launch ----------------

extern "C" void kernel_launch(void* const* d_in, const int* in_sizes, int n_in,
                              void* d_out, int out_size, void* d_ws, size_t ws_size,
                              hipStream_t stream) {
  const float* features = (const float*)d_in[0];
  const int*   src      = (const int*)d_in[1];
  const int*   dst      = (const int*)d_in[2];
  const float* w_in     = (const float*)d_in[3];
  const float* b_in     = (const float*)d_in[4];
  const float* gc_w     = (const float*)d_in[5];
  const float* gc_b     = (const float*)d_in[6];
  const float* bn_gamma = (const float*)d_in[7];
  const float* bn_beta  = (const float*)d_in[8];
  const float* bn_mean  = (const float*)d_in[9];
  const float* bn_var   = (const float*)d_in[10];
  const float* attn_w1  = (const float*)d_in[11];
  const float* attn_b1  = (const float*)d_in[12];
  const float* attn_w2  = (const float*)d_in[13];
  const float* attn_b2  = (const float*)d_in[14];
  const float* agg_w    = (const float*)d_in[15];
  const float* agg_b    = (const float*)d_in[16];
  const float* out_w    = (const float*)d_in[17];
  const float* out_b    = (const float*)d_in[18];
  float* out = (float*)d_out;

  float* fbase   = (float*)d_ws;
  float* W0 = fbase;                 // h0 -> spmm scratch
  float* W1 = fbase + NH;            // neigh -> a -> h_att -> h(final)
  float* W2 = fbase + 2 * NH;        // agg -> h(L0) -> h(L2)
  float* inv_mean = fbase + 3 * NH;
  float* inv_in   = inv_mean + NN;
  float* inv_out  = inv_in + NN;
  int* indeg   = (int*)(inv_out + NN);
  int* row_ptr = indeg + NN;         // NN+1
  int* bsum    = row_ptr + NN + 1;   // 256
  int* col     = bsum + 256;         // EE

  // preprocessing scratch aliased into W1 (only used before W1's first write)
  unsigned* pd   = (unsigned*)W1;             // NSL*NN = 6.4MB
  unsigned* ps   = pd + (long)NSL * NN;       // 6.4MB
  unsigned* cur0 = ps + (long)NSL * NN;       // 6.4MB

  // packed bf16 hi/lo weights
  ushort* pk = (ushort*)(col + EE);
  const int SZ256 = 8 * 8 * 512;     // K=256, NT=8
  const int SZ128 = 4 * 8 * 512;     // K=128, NT=8
  const int SZOUT = 4 * 4 * 512;     // K=128, NT=4
  ushort* win_hi = pk;  pk += SZ256;  ushort* win_lo = pk;  pk += SZ256;
  ushort* agg_hi = pk;  pk += SZ256;  ushort* agg_lo = pk;  pk += SZ256;
  ushort* at1_hi = pk;  pk += SZ256;  ushort* at1_lo = pk;  pk += SZ256;
  ushort* gch[3], *gcl[3];
  for (int i = 0; i < 3; ++i) { gch[i] = pk; pk += SZ128; gcl[i] = pk; pk += SZ128; }
  ushort* ow_hi = pk;  pk += SZOUT;   ushort* ow_lo = pk;  pk += SZOUT;
  __half* X16 = (__half*)pk;          // NH halfs, sliced [4][NN][32]

  dim3 b256(256), b128(128);
  const int gN = (NN + 255) / 256;
  const int gblocks = (NN + 127) / 128;
  const int gspmm = (NN / 8) * 8;     // 50000 blocks: (node-group)*8 + xcd
  const int gpre = NSL * 4;

  // graph preprocessing (no global atomics)
  count_partial_kernel<<<gpre, b256, 0, stream>>>((const int4*)dst, pd);
  count_partial_kernel<<<gpre, b256, 0, stream>>>((const int4*)src, ps);
  reduce_deg_kernel<<<gN, b256, 0, stream>>>(pd, ps, indeg, inv_mean, inv_in, inv_out);
  scan_block_kernel<<<gN, b256, 0, stream>>>(indeg, row_ptr, bsum, NN);
  scan_block_kernel<<<1, b256, 0, stream>>>(bsum, bsum, nullptr, gN);
  cursor_init_kernel<<<gN, b256, 0, stream>>>(row_ptr, bsum, pd, cur0);
  fill_partial_kernel<<<gpre, b256, 0, stream>>>((const int4*)dst, (const int4*)src, cur0, col);

  // weight prepack
  prepack_kernel<<<(SZ256 + 255) / 256, b256, 0, stream>>>(w_in,    HF, HF, 8, win_hi, win_lo, SZ256);
  prepack_kernel<<<(SZ256 + 255) / 256, b256, 0, stream>>>(agg_w,   HF, HF, 8, agg_hi, agg_lo, SZ256);
  prepack_kernel<<<(SZ256 + 255) / 256, b256, 0, stream>>>(attn_w1, HF, HF, 8, at1_hi, at1_lo, SZ256);
  for (int i = 0; i < 3; ++i)
    prepack_kernel<<<(SZ128 + 255) / 256, b256, 0, stream>>>(gc_w + (long)i * HF * HF, HF, HF, 8, gch[i], gcl[i], SZ128);
  prepack_kernel<<<(SZOUT + 255) / 256, b256, 0, stream>>>(out_w, CC, CC, 4, ow_hi, ow_lo, SZOUT);

  // h0 = relu(features @ w_in + b_in)            -> W0 (+fp16 raw sliced -> X16)
  mgemm_kernel<8, 8, EPI_RELU, H16_RAW><<<gblocks, b256, 0, stream>>>(
      features, INF_, features + 128, INF_, win_hi, win_lo, b_in,
      nullptr, nullptr, nullptr, nullptr, nullptr, W0, HF, HF, X16, nullptr);
  // neigh = mean-agg(h0)                          -> W1
  spmm32s_kernel<<<gspmm, b256, 0, stream>>>(row_ptr, col, X16, inv_mean, W1);
  // agg = relu([h0|neigh] @ agg_w + agg_b)        -> W2
  mgemm_kernel<8, 8, EPI_RELU, H16_NONE><<<gblocks, b256, 0, stream>>>(
      W0, HF, W1, HF, agg_hi, agg_lo, agg_b,
      nullptr, nullptr, nullptr, nullptr, nullptr, W2, HF, HF, nullptr, nullptr);
  // a = relu([h0|agg] @ attn_w1 + attn_b1)        -> W1
  mgemm_kernel<8, 8, EPI_RELU, H16_NONE><<<gblocks, b256, 0, stream>>>(
      W0, HF, W2, HF, at1_hi, at1_lo, attn_b1,
      nullptr, nullptr, nullptr, nullptr, nullptr, W1, HF, HF, nullptr, nullptr);
  // h_att = h0 + agg * sigmoid(a@w2+b2)           -> W1 (+fp16 *inv_out sliced -> X16)
  attn_hatt_kernel<<<NN, b128, 0, stream>>>(W1, attn_w2, attn_b2, W0, W2, inv_out, W1, X16);

  // layer 0: spmm(X16)->W0 ; relu(BN(W0@gc0+b0))          -> W2 (+fp16 -> X16)
  spmm32s_kernel<<<gspmm, b256, 0, stream>>>(row_ptr, col, X16, inv_in, W0);
  mgemm_kernel<4, 8, EPI_BN, H16_SCALED><<<gblocks, b256, 0, stream>>>(
      W0, HF, nullptr, 0, gch[0], gcl[0], gc_b,
      bn_gamma, bn_beta, bn_mean, bn_var, nullptr, W2, HF, HF, X16, inv_out);
  // layer 1: spmm(X16)->W0 ; relu(BN(W0@gc1+b1)) + W2     -> W1 (+fp16 -> X16)
  spmm32s_kernel<<<gspmm, b256, 0, stream>>>(row_ptr, col, X16, inv_in, W0);
  mgemm_kernel<4, 8, EPI_BN_RES, H16_SCALED><<<gblocks, b256, 0, stream>>>(
      W0, HF, nullptr, 0, gch[1], gcl[1], gc_b + HF,
      bn_gamma + HF, bn_beta + HF, bn_mean + HF, bn_var + HF, W2, W1, HF, HF, X16, inv_out);
  // layer 2: spmm(X16)->W0 ; relu(BN(W0@gc2+b2)) + W1     -> W2
  spmm32s_kernel<<<gspmm, b256, 0, stream>>>(row_ptr, col, X16, inv_in, W0);
  mgemm_kernel<4, 8, EPI_BN_RES, H16_NONE><<<gblocks, b256, 0, stream>>>(
      W0, HF, nullptr, 0, gch[2], gcl[2], gc_b + 2 * HF,
      bn_gamma + 2 * HF, bn_beta + 2 * HF, bn_mean + 2 * HF, bn_var + 2 * HF, W1, W2, HF, HF,
      nullptr, nullptr);

  // out = W2 @ out_w + out_b                      -> d_out
  mgemm_kernel<4, 4, EPI_NONE, H16_NONE><<<gblocks, b256, 0, stream>>>(
      W2, HF, nullptr, 0, ow_hi, ow_lo, out_b,
      nullptr, nullptr, nullptr, nullptr, nullptr, out, CC, CC, nullptr, nullptr);
}